// Round 10
// baseline (561.429 us; speedup 1.0000x reference)
//
#include <hip/hip_runtime.h>
#include <hip/hip_bf16.h>

// GPT-2 transformer block, MI355X bf16-MFMA. Round 17:
//  - attn_mfma: UNPAIRED q-tiles, 2048 blocks (one 64-row q-tile each).
//    R9 (1024 paired blocks) = 96us, VALU 66% — chain-bound with residency
//    grid-capped at 4 blocks/CU while LDS (32KB) allows 5. Unpairing gives
//    2048 blocks -> 5 resident blocks/CU (+25% waves) and a single process
//    per k-tile iteration (shorter barrier interval). Causal non-uniformity
//    (block qi does qi+1 k-tiles) handled by BIG-FIRST dispatch order:
//    qi = 31 - ((id>>3)&31), so the tail is the 1-tile blocks.
//    XCD grouping kept: id = (g&7) + 8*t + 256*(g>>3), g=h+16b -> all 32
//    blocks of one (b,h) on one XCD (FETCH stays ~25MB). NO launch_bounds
//    min-waves cap (R7/R8 lesson: the 128-VGPR cap killed the container).
//  - in-register P (R13): swapped QK^T + K-row permutation pi(aa,kc,m) =
//    8*(m>>2)+(m&3)+4*aa+32*kc makes st(quad,r) hold k=8quad+(r+4aa)+32kc;
//    pk2b packs PV A-frags in-lane; P never touches LDS.
//  - Ks/Vts: LD=64, store-side XOR swizzle f(row)=(row&3)|((row>>3&1)<<2),
//    double-buffered, one barrier per k-tile. Conflict-free (0 confl).
//  - gemm256 per-phase pipeline (T2+T3+T4+T5), split-K=2 + LN fusion:
//    unchanged from R11.

typedef __attribute__((ext_vector_type(8))) short bf16x8;  // MFMA A/B frag
typedef __attribute__((ext_vector_type(4))) float f32x4;   // MFMA C/D frag

__device__ __forceinline__ unsigned short f2b(float f) {  // RNE
  unsigned int u = __float_as_uint(f);
  u += 0x7fffu + ((u >> 16) & 1u);
  return (unsigned short)(u >> 16);
}
__device__ __forceinline__ unsigned int pk2b(float a, float b) {  // packed bf16x2
  __hip_bfloat162 h = __float22bfloat162_rn(make_float2(a, b));
  return *(unsigned int*)&h;
}
__device__ __forceinline__ void gload_lds16(const unsigned short* g, unsigned short* l) {
  __builtin_amdgcn_global_load_lds((const __attribute__((address_space(1))) void*)g,
                                   (__attribute__((address_space(3))) void*)l, 16, 0, 0);
}

// ---------------- fp32 -> bf16 elementwise ----------------
__global__ __launch_bounds__(256) void cvt_bf16(const float* __restrict__ in,
                                                unsigned short* __restrict__ out, long n) {
  long i = ((long)blockIdx.x * 256 + threadIdx.x) * 4;
  if (i >= n) return;
  float4 v = *(const float4*)(in + i);
  *(ushort4*)(out + i) = make_ushort4(f2b(v.x), f2b(v.y), f2b(v.z), f2b(v.w));
}

// ---------------- transpose fp32 [R,C] -> bf16 [C,R] ----------------
__global__ __launch_bounds__(256) void transpose_bf16(const float* __restrict__ in,
                                                      unsigned short* __restrict__ out,
                                                      int R, int C) {
  __shared__ float tile[32][33];
  int c0 = blockIdx.x * 32, r0 = blockIdx.y * 32;
  for (int i = threadIdx.y; i < 32; i += 8)
    tile[i][threadIdx.x] = in[(long)(r0 + i) * C + c0 + threadIdx.x];
  __syncthreads();
  for (int i = threadIdx.y; i < 32; i += 8)
    out[(long)(c0 + i) * R + r0 + threadIdx.x] = f2b(tile[threadIdx.x][i]);
}

// ---------------- 256^2 per-phase-pipelined bf16 MFMA GEMM ----------------
// A [M][Kstride] bf16, Bt [N][Kstride] bf16. K = chunk length, blockIdx.y =
// K-chunk (0 -> Cout +bias, 1 -> Cout2 raw partial). M fixed 8192.
// Requires K%32==0, K>=128, N%256==0, gridDim.x%8==0.
// EPI: 0=f32 out, 2=bf16+relu,
//      3=qkv split: gn<2048 -> qk[m][2048] (q cols scaled 0.125*log2e),
//                   gn>=2048 -> vt[b,h,s,t] packed ushort4 scatter.
template <int EPI>
__global__ __launch_bounds__(512, 2) void gemm256(const unsigned short* __restrict__ A,
                                                  const unsigned short* __restrict__ Bt,
                                                  const float* __restrict__ bias,
                                                  void* __restrict__ Cout,
                                                  void* __restrict__ Cout2,
                                                  int N, int K, int Kstride) {
  __shared__ __align__(16) unsigned short As[4][256 * 32];  // 64 KiB ring
  __shared__ __align__(16) unsigned short Bs[4][256 * 32];  // 64 KiB ring

  int tid = threadIdx.x;
  int wv = tid >> 6, lane = tid & 63, quad = lane >> 4, l16 = lane & 15;
  int wm = wv >> 2, wn = wv & 3;  // 2x4 wave grid; wave owns 128x64 of C

  // XCD-aware bijective swizzle (gridDim.x % 8 == 0), bm-fastest
  int nwg = gridDim.x, id = blockIdx.x;
  int sid = (id & 7) * (nwg >> 3) + (id >> 3);
  int bm256 = (sid & 31) * 256, bn256 = (sid >> 5) * 256;
  int chunk = blockIdx.y;
  long kbase = (long)chunk * K;

  // staging: tile = 256 rows x 32 cols; thread covers 16B chunks tid and
  // tid+512. LDS chunk (row, slot) holds global chunk d = slot ^ ((row>>1)&3).
  int row1 = tid >> 2, row2 = row1 + 128;
  long dsl = ((tid & 3) ^ ((tid >> 3) & 3)) * 8;  // inverse-swizzled source col
  const unsigned short* Ap1 = A + (long)(bm256 + row1) * Kstride + kbase + dsl;
  const unsigned short* Ap2 = A + (long)(bm256 + row2) * Kstride + kbase + dsl;
  const unsigned short* Bp1 = Bt + (long)(bn256 + row1) * Kstride + kbase + dsl;
  const unsigned short* Bp2 = Bt + (long)(bn256 + row2) * Kstride + kbase + dsl;
  int lo1 = wv * 512, lo2 = wv * 512 + 4096;

  f32x4 acc[8][4] = {};
  // read-side swizzled 16B slot: (quad ^ ((row>>1)&3))*8, row%16 == l16
  int sl8 = (quad ^ ((l16 >> 1) & 3)) * 8;
  int arow = wm * 128 + l16;  // + i*16
  int brow = wn * 64 + l16;   // + j*16

  int NT = K >> 5;  // always >= 16 here
  // prologue stages, issue order A0 B0 A1 B1 A2 (10 loads; newest 6 may fly)
  gload_lds16(Ap1, &As[0][lo1]); gload_lds16(Ap2, &As[0][lo2]);
  gload_lds16(Bp1, &Bs[0][lo1]); gload_lds16(Bp2, &Bs[0][lo2]);
  gload_lds16(Ap1 + 32, &As[1][lo1]); gload_lds16(Ap2 + 32, &As[1][lo2]);
  gload_lds16(Bp1 + 32, &Bs[1][lo1]); gload_lds16(Bp2 + 32, &Bs[1][lo2]);
  gload_lds16(Ap1 + 64, &As[2][lo1]); gload_lds16(Ap2 + 64, &As[2][lo2]);
  asm volatile("s_waitcnt vmcnt(6)\n\ts_barrier" ::: "memory");
  __builtin_amdgcn_sched_barrier(0);

  for (int tau = 0; tau < NT; ++tau) {
    const unsigned short* Ab = &As[tau & 3][0];
    const unsigned short* Bb = &Bs[tau & 3][0];
    bf16x8 af[4], bfr[4];
    // ---- even phase: read A i0-3 + B j0-3 (8 b128); stage B(tau+2); MFMA i0-3
#pragma unroll
    for (int i = 0; i < 4; ++i)
      af[i] = *(const bf16x8*)(Ab + (arow + i * 16) * 32 + sl8);
#pragma unroll
    for (int j = 0; j < 4; ++j)
      bfr[j] = *(const bf16x8*)(Bb + (brow + j * 16) * 32 + sl8);
    if (tau + 2 < NT) {
      long ko = (long)(tau + 2) * 32;
      int s = (tau + 2) & 3;
      gload_lds16(Bp1 + ko, &Bs[s][lo1]);
      gload_lds16(Bp2 + ko, &Bs[s][lo2]);
    }
    asm volatile("s_barrier\n\ts_waitcnt lgkmcnt(0)" ::: "memory");
    __builtin_amdgcn_sched_barrier(0);
    __builtin_amdgcn_s_setprio(1);
#pragma unroll
    for (int i = 0; i < 4; ++i)
#pragma unroll
      for (int j = 0; j < 4; ++j)
        acc[i][j] = __builtin_amdgcn_mfma_f32_16x16x32_bf16(af[i], bfr[j], acc[i][j], 0, 0, 0);
    __builtin_amdgcn_s_setprio(0);
    __builtin_amdgcn_s_barrier();
    __builtin_amdgcn_sched_barrier(0);
    // ---- odd phase: read A i4-7 (4 b128); stage A(tau+3); MFMA i4-7
    bf16x8 ag[4];
#pragma unroll
    for (int i = 0; i < 4; ++i)
      ag[i] = *(const bf16x8*)(Ab + (arow + (i + 4) * 16) * 32 + sl8);
    if (tau + 3 < NT) {
      long ko = (long)(tau + 3) * 32;
      int s = (tau + 3) & 3;
      gload_lds16(Ap1 + ko, &As[s][lo1]);
      gload_lds16(Ap2 + ko, &As[s][lo2]);
    }
    asm volatile("s_barrier\n\ts_waitcnt lgkmcnt(0)" ::: "memory");
    __builtin_amdgcn_sched_barrier(0);
    __builtin_amdgcn_s_setprio(1);
#pragma unroll
    for (int i = 0; i < 4; ++i)
#pragma unroll
      for (int j = 0; j < 4; ++j)
        acc[i + 4][j] = __builtin_amdgcn_mfma_f32_16x16x32_bf16(ag[i], bfr[j], acc[i + 4][j], 0, 0, 0);
    __builtin_amdgcn_s_setprio(0);
    // ---- once-per-tile counted gate + end barrier (tail: 6 -> 4 -> 0)
    if (tau + 3 < NT) {
      asm volatile("s_waitcnt vmcnt(6)\n\ts_barrier" ::: "memory");
    } else if (tau + 2 < NT) {
      asm volatile("s_waitcnt vmcnt(4)\n\ts_barrier" ::: "memory");
    } else if (tau + 1 < NT) {
      asm volatile("s_waitcnt vmcnt(0)\n\ts_barrier" ::: "memory");
    }
    __builtin_amdgcn_sched_barrier(0);
  }

  void* Cbase = chunk ? Cout2 : Cout;
#pragma unroll
  for (int i = 0; i < 8; ++i) {
#pragma unroll
    for (int j = 0; j < 4; ++j) {
      int gn = bn256 + wn * 64 + j * 16 + l16;
      float bv = chunk ? 0.f : bias[gn];
      if (EPI == 3 && gn >= 2048) {
        int h = (gn >> 6) & 15, s = gn & 63;
        int gm0 = bm256 + wm * 128 + i * 16 + quad * 4;
        int b = gm0 >> 11, tt0 = gm0 & 2047;
        unsigned short* vt = (unsigned short*)Cout + 16777216L;
        ushort4 us;
        us.x = f2b(acc[i][j][0] + bv);
        us.y = f2b(acc[i][j][1] + bv);
        us.z = f2b(acc[i][j][2] + bv);
        us.w = f2b(acc[i][j][3] + bv);
        *(ushort4*)(vt + (((long)(b * 16 + h)) * 64 + s) * 2048 + tt0) = us;
      } else {
#pragma unroll
        for (int r = 0; r < 4; ++r) {
          int gm = bm256 + wm * 128 + i * 16 + quad * 4 + r;
          float v = acc[i][j][r] + bv;
          if (EPI == 2) v = fmaxf(v, 0.f);
          if (EPI == 0) {
            ((float*)Cbase)[(long)gm * N + gn] = v;
          } else if (EPI == 2) {
            ((unsigned short*)Cbase)[(long)gm * N + gn] = f2b(v);
          } else {  // EPI==3, q/k rows
            float sc = (gn < 1024) ? 0.18033688011112042f : 1.0f;  // 0.125*log2(e)
            ((unsigned short*)Cbase)[(long)gm * 2048 + gn] = f2b(v * sc);
          }
        }
      }
    }
  }
}

// ---------------- MFMA flash attention (reg-P, unpaired big-first q-tiles) ----
// qk[m][2048] (q cols 0..1023 pre-scaled by 0.125*log2e, k cols 1024..2047),
// vt[b,h,s,t] at elem offset 16M. 1-D grid 2048, 256 thr = 4 waves.
// id = (g&7) + 8*t + 256*(g>>3), g = h + 16*b, qi = 31 - t: all 32 blocks of
// one (b,h) share an XCD; heaviest blocks (qi=31) dispatch first so the
// causal tail (1-tile blocks) back-fills. Block: ONE 64-row q-tile qi,
// k-tiles 0..qi. Wave w owns q rows [qi*64 + w*16, +16). P in-register.
__global__ __launch_bounds__(256) void attn_mfma(const unsigned short* __restrict__ qkv,
                                                 unsigned short* __restrict__ outp) {
  __shared__ __align__(16) unsigned short Ks[2][64 * 64];
  __shared__ __align__(16) unsigned short Vts[2][64 * 64];
  int id = blockIdx.x;
  int g = (id & 7) | ((id >> 8) << 3);
  int qi = 31 - ((id >> 3) & 31);
  int h = g & 15, b = g >> 4;
  int t = threadIdx.x;
  int w = t >> 6, lane = t & 63, quad = lane >> 4, l16 = lane & 15;
  const unsigned short* qg = qkv + (long)(b * 2048) * 2048 + h * 64;
  const unsigned short* kg = qg + 1024;
  const unsigned short* vg = qkv + 16777216L + (((long)(b * 16 + h)) * 64) * 2048;

  // Q frags (B-operand for S^T): [ks]; row = qi*64 + w*16 + l16
  bf16x8 qf[2];
#pragma unroll
  for (int ks = 0; ks < 2; ++ks)
    qf[ks] = *(const bf16x8*)(qg + (long)(qi * 64 + w * 16 + l16) * 2048 + ks * 32 + quad * 8);

  int sr = t >> 2, c4 = t & 3;
  int fsr = (sr & 3) | (((sr >> 3) & 1) << 2);          // store-side swizzle
  int ws0 = sr * 64 + (((2 * c4) ^ fsr) * 8);           // slot 2c
  int ws1 = sr * 64 + (((2 * c4 + 1) ^ fsr) * 8);       // slot 2c+1
  const unsigned short* kp = kg + (long)sr * 2048 + c4 * 16;
  const unsigned short* vp = vg + (long)sr * 2048 + c4 * 16;
  int4 kv0 = *(const int4*)kp, kv1 = *(const int4*)(kp + 8);
  int4 vv0 = *(const int4*)vp, vv1 = *(const int4*)(vp + 8);
  kp += (long)64 * 2048;
  vp += 64;

  f32x4 oa[4] = {};
  f32x4 la = {};
  const short ONE = 0x3F80;
  bf16x8 ones = {ONE, ONE, ONE, ONE, ONE, ONE, ONE, ONE};

  int fs = l16 & 7;                                     // f(pi-row) for K reads
  int fv = (l16 & 3) | (((l16 >> 3) & 1) << 2);         // f(row) for V reads
  int qrow = w * 16 + l16;                              // q row within 64-tile

  int nkt = qi + 1;
  for (int kt = 0; kt < nkt; ++kt) {
    unsigned short* Kb = &Ks[kt & 1][0];
    unsigned short* Vb = &Vts[kt & 1][0];
    *(int4*)(Kb + ws0) = kv0;
    *(int4*)(Kb + ws1) = kv1;
    *(int4*)(Vb + ws0) = vv0;
    *(int4*)(Vb + ws1) = vv1;
    __syncthreads();
    if (kt + 1 < nkt) {  // prefetch next tile behind compute
      kv0 = *(const int4*)kp; kv1 = *(const int4*)(kp + 8);
      vv0 = *(const int4*)vp; vv1 = *(const int4*)(vp + 8);
      kp += (long)64 * 2048;
      vp += 64;
    }
    // one k-tile (64 k) x 16 q rows, P fully in-register
    bool diag = (kt == qi);
#pragma unroll
    for (int kc = 0; kc < 2; ++kc) {
      unsigned int apw[4];
#pragma unroll
      for (int aa = 0; aa < 2; ++aa) {
        int row = 8 * (l16 >> 2) + (l16 & 3) + 4 * aa + 32 * kc;  // pi(aa,kc,l16)
        const unsigned short* kr = Kb + row * 64;
        bf16x8 kf0 = *(const bf16x8*)(kr + (quad ^ fs) * 8);
        bf16x8 kf1 = *(const bf16x8*)(kr + ((quad ^ 4 ^ fs)) * 8);
        f32x4 st = {};
        st = __builtin_amdgcn_mfma_f32_16x16x32_bf16(kf0, qf[0], st, 0, 0, 0);
        st = __builtin_amdgcn_mfma_f32_16x16x32_bf16(kf1, qf[1], st, 0, 0, 0);
        if (diag) {
          int kq = 8 * quad + 4 * aa + 32 * kc;
#pragma unroll
          for (int r = 0; r < 4; ++r)
            if (kq + r > qrow) st[r] = -1e30f;
        }
        apw[aa * 2]     = pk2b(exp2f(st[0]), exp2f(st[1]));
        apw[aa * 2 + 1] = pk2b(exp2f(st[2]), exp2f(st[3]));
      }
      union { unsigned int u[4]; bf16x8 v; } ap;
#pragma unroll
      for (int u = 0; u < 4; ++u) ap.u[u] = apw[u];
      la = __builtin_amdgcn_mfma_f32_16x16x32_bf16(ap.v, ones, la, 0, 0, 0);
#pragma unroll
      for (int sg = 0; sg < 4; ++sg) {
        int vrow = sg * 16 + l16;
        bf16x8 vf = *(const bf16x8*)(Vb + vrow * 64 + (((4 * kc + quad) ^ fv) * 8));
        oa[sg] = __builtin_amdgcn_mfma_f32_16x16x32_bf16(ap.v, vf, oa[sg], 0, 0, 0);
      }
    }
  }

#pragma unroll
  for (int r = 0; r < 4; ++r) {
    float invl = 1.f / la[r];
    int row = qi * 64 + w * 16 + quad * 4 + r;
    unsigned short* op = outp + ((long)(b * 2048 + row)) * 1024 + h * 64;
#pragma unroll
    for (int sg = 0; sg < 4; ++sg) op[sg * 16 + l16] = f2b(oa[sg][r] * invl);
  }
}

// ---------------- residual + LayerNorm (optional 3rd addend: split-K partial) --
__global__ __launch_bounds__(256) void ln_kernel(const float* __restrict__ a,
                                                 const float* __restrict__ a2,
                                                 const float* __restrict__ res,
                                                 const float* __restrict__ gam,
                                                 const float* __restrict__ bet,
                                                 float* __restrict__ outf,
                                                 unsigned short* __restrict__ outb) {
  int row = blockIdx.x, t = threadIdx.x;
  float4 av = *(const float4*)(a + (long)row * 1024 + t * 4);
  float4 rv = *(const float4*)(res + (long)row * 1024 + t * 4);
  float v0 = av.x + rv.x, v1 = av.y + rv.y, v2 = av.z + rv.z, v3 = av.w + rv.w;
  if (a2) {
    float4 a2v = *(const float4*)(a2 + (long)row * 1024 + t * 4);
    v0 += a2v.x; v1 += a2v.y; v2 += a2v.z; v3 += a2v.w;
  }
  float s = v0 + v1 + v2 + v3;
  float ss = v0 * v0 + v1 * v1 + v2 * v2 + v3 * v3;
#pragma unroll
  for (int off = 32; off >= 1; off >>= 1) {
    s += __shfl_down(s, off);
    ss += __shfl_down(ss, off);
  }
  __shared__ float sb[4], ssb[4];
  __shared__ float mean_s, inv_s;
  int w = t >> 6, lane = t & 63;
  if (lane == 0) { sb[w] = s; ssb[w] = ss; }
  __syncthreads();
  if (t == 0) {
    float S = sb[0] + sb[1] + sb[2] + sb[3];
    float SS = ssb[0] + ssb[1] + ssb[2] + ssb[3];
    float mean = S * (1.f / 1024.f);
    float var = SS * (1.f / 1024.f) - mean * mean;
    mean_s = mean;
    inv_s = rsqrtf(var + 1e-5f);
  }
  __syncthreads();
  float mean = mean_s, inv = inv_s;
  int c = t * 4;
  float4 gv = *(const float4*)(gam + c);
  float4 bv = *(const float4*)(bet + c);
  float y0 = (v0 - mean) * inv * gv.x + bv.x;
  float y1 = (v1 - mean) * inv * gv.y + bv.y;
  float y2 = (v2 - mean) * inv * gv.z + bv.z;
  float y3 = (v3 - mean) * inv * gv.w + bv.w;
  *(float4*)(outf + (long)row * 1024 + c) = make_float4(y0, y1, y2, y3);
  if (outb) {
    *(ushort4*)(outb + (long)row * 1024 + c) = make_ushort4(f2b(y0), f2b(y1), f2b(y2), f2b(y3));
  }
}

extern "C" void kernel_launch(void* const* d_in, const int* in_sizes, int n_in,
                              void* d_out, int out_size, void* d_ws, size_t ws_size,
                              hipStream_t stream) {
  const float* x      = (const float*)d_in[0];
  const float* w_attn = (const float*)d_in[1];
  const float* b_attn = (const float*)d_in[2];
  const float* w_proj = (const float*)d_in[3];
  const float* b_proj = (const float*)d_in[4];
  const float* ln1_g  = (const float*)d_in[5];
  const float* ln1_b  = (const float*)d_in[6];
  const float* w_ff1  = (const float*)d_in[7];
  const float* b_ff1  = (const float*)d_in[8];
  const float* w_ff2  = (const float*)d_in[9];
  const float* b_ff2  = (const float*)d_in[10];
  const float* ln2_g  = (const float*)d_in[11];
  const float* ln2_b  = (const float*)d_in[12];

  const long M = 8192, E = 1024;
  char* ws = (char*)d_ws;
  unsigned short* xb   = (unsigned short*)ws; ws += M * E * 2;           // 16 MiB
  unsigned short* wTa  = (unsigned short*)ws; ws += 3072L * 1024 * 2;    // 6
  unsigned short* wTp  = (unsigned short*)ws; ws += 1024L * 1024 * 2;    // 2
  unsigned short* wTf1 = (unsigned short*)ws; ws += 4096L * 1024 * 2;    // 8
  unsigned short* wTf2 = (unsigned short*)ws; ws += 4096L * 1024 * 2;    // 8
  unsigned short* qkvb = (unsigned short*)ws; ws += M * 3072 * 2;        // 48 (qk rows 32 MiB | vt 16 MiB)
  unsigned short* attb = (unsigned short*)ws; ws += M * E * 2;           // 16
  float* a1f = (float*)ws; ws += M * E * 4;                              // 32
  float* x1f = (float*)ws; ws += M * E * 4;                              // 32
  unsigned short* x1b = (unsigned short*)ws; ws += M * E * 2;            // 16  => 184 MiB
  unsigned short* hb = qkvb;   // overlays consumed qkv+attb space
  float* f2 = a1f;
  // split-K partial buffers (reuse dead workspace, both 32 MiB fp32):
  float* prj1 = (float*)qkvb;   // qk region dead after attn; ln1 consumes before ff1
  float* ff21 = (float*)d_ws;   // xb+wTa+wTp+(part of)wTf1 dead by ff2

  cvt_bf16<<<dim3((M * E) / 4 / 256), dim3(256), 0, stream>>>(x, xb, M * E);
  transpose_bf16<<<dim3(3072 / 32, 1024 / 32), dim3(32, 8), 0, stream>>>(w_attn, wTa, 1024, 3072);
  transpose_bf16<<<dim3(1024 / 32, 1024 / 32), dim3(32, 8), 0, stream>>>(w_proj, wTp, 1024, 1024);
  transpose_bf16<<<dim3(4096 / 32, 1024 / 32), dim3(32, 8), 0, stream>>>(w_ff1, wTf1, 1024, 4096);
  transpose_bf16<<<dim3(1024 / 32, 4096 / 32), dim3(32, 8), 0, stream>>>(w_ff2, wTf2, 4096, 1024);
  // qkv projection (384 blocks), attention-layout epilogue
  gemm256<3><<<dim3(384, 1), dim3(512), 0, stream>>>(xb, wTa, b_attn, qkvb, nullptr, 3072, 1024, 1024);
  // MFMA flash attention (reg-P, unpaired big-first q-tiles, 2048 blocks)
  attn_mfma<<<dim3(2048), dim3(256), 0, stream>>>(qkvb, attb);
  // attn output projection: split-K=2 -> 256 blocks = 1 full round
  gemm256<0><<<dim3(128, 2), dim3(512), 0, stream>>>(attb, wTp, b_proj, a1f, prj1, 1024, 512, 1024);
  ln_kernel<<<dim3(8192), dim3(256), 0, stream>>>(a1f, prj1, x, ln1_g, ln1_b, x1f, x1b);
  // ff1 (512 blocks = 2 rounds)
  gemm256<2><<<dim3(512, 1), dim3(512), 0, stream>>>(x1b, wTf1, b_ff1, hb, nullptr, 4096, 1024, 1024);
  // ff2: split-K=2 -> 256 blocks = 1 full round, K chunks of 2048
  gemm256<0><<<dim3(128, 2), dim3(512), 0, stream>>>(hb, wTf2, b_ff2, f2, ff21, 1024, 2048, 4096);
  ln_kernel<<<dim3(8192), dim3(256), 0, stream>>>(f2, ff21, x1f, ln2_g, ln2_b, (float*)d_out, nullptr);
}

// Round 11
// 554.875 us; speedup vs baseline: 1.0118x; 1.0118x over previous
//
#include <hip/hip_runtime.h>
#include <hip/hip_bf16.h>

// GPT-2 transformer block, MI355X bf16-MFMA. Round 18:
//  - attn_mfma: R9's paired 1024-block kernel (best measured: 96us) with the
//    heavy+light processes FUSED per k-tile. R10 showed unpairing regressed
//    (96->104) despite +occupancy: the paired second process is free ILP
//    between barriers. Fusion goes further: K-frags and V-frags are read
//    from LDS ONCE and feed BOTH q-tiles' MFMAs (K/V LDS reads and addr
//    arith halved in the shared half of the loop), and the two independent
//    MFMA->exp2->pack chains interleave (T15 mechanism without extra
//    buffers). No launch_bounds min-waves cap (R7/R8 container lesson);
//    VGPR must stay <=128 for 4 blocks/CU.
//  - in-register P: swapped QK^T + K-row permutation pi(aa,kc,m) =
//    8*(m>>2)+(m&3)+4*aa+32*kc makes st(quad,r) hold k=8quad+(r+4aa)+32kc;
//    pk2b packs PV A-frags in-lane; P never touches LDS.
//  - Ks/Vts: LD=64, store-side XOR swizzle f(row)=(row&3)|((row>>3&1)<<2),
//    double-buffered, one barrier per k-tile. Conflict-free (0 confl).
//  - XCD grouping: id=(g&7)+8*qa+128*(g>>3) -> all pair-blocks of a (b,h)
//    on one XCD (FETCH ~25MB).
//  - gemm256 per-phase pipeline (T2+T3+T4+T5), split-K=2 + LN fusion:
//    unchanged from R11.

typedef __attribute__((ext_vector_type(8))) short bf16x8;  // MFMA A/B frag
typedef __attribute__((ext_vector_type(4))) float f32x4;   // MFMA C/D frag

__device__ __forceinline__ unsigned short f2b(float f) {  // RNE
  unsigned int u = __float_as_uint(f);
  u += 0x7fffu + ((u >> 16) & 1u);
  return (unsigned short)(u >> 16);
}
__device__ __forceinline__ unsigned int pk2b(float a, float b) {  // packed bf16x2
  __hip_bfloat162 h = __float22bfloat162_rn(make_float2(a, b));
  return *(unsigned int*)&h;
}
__device__ __forceinline__ void gload_lds16(const unsigned short* g, unsigned short* l) {
  __builtin_amdgcn_global_load_lds((const __attribute__((address_space(1))) void*)g,
                                   (__attribute__((address_space(3))) void*)l, 16, 0, 0);
}

// ---------------- fp32 -> bf16 elementwise ----------------
__global__ __launch_bounds__(256) void cvt_bf16(const float* __restrict__ in,
                                                unsigned short* __restrict__ out, long n) {
  long i = ((long)blockIdx.x * 256 + threadIdx.x) * 4;
  if (i >= n) return;
  float4 v = *(const float4*)(in + i);
  *(ushort4*)(out + i) = make_ushort4(f2b(v.x), f2b(v.y), f2b(v.z), f2b(v.w));
}

// ---------------- transpose fp32 [R,C] -> bf16 [C,R] ----------------
__global__ __launch_bounds__(256) void transpose_bf16(const float* __restrict__ in,
                                                      unsigned short* __restrict__ out,
                                                      int R, int C) {
  __shared__ float tile[32][33];
  int c0 = blockIdx.x * 32, r0 = blockIdx.y * 32;
  for (int i = threadIdx.y; i < 32; i += 8)
    tile[i][threadIdx.x] = in[(long)(r0 + i) * C + c0 + threadIdx.x];
  __syncthreads();
  for (int i = threadIdx.y; i < 32; i += 8)
    out[(long)(c0 + i) * R + r0 + threadIdx.x] = f2b(tile[threadIdx.x][i]);
}

// ---------------- 256^2 per-phase-pipelined bf16 MFMA GEMM ----------------
// A [M][Kstride] bf16, Bt [N][Kstride] bf16. K = chunk length, blockIdx.y =
// K-chunk (0 -> Cout +bias, 1 -> Cout2 raw partial). M fixed 8192.
// Requires K%32==0, K>=128, N%256==0, gridDim.x%8==0.
// EPI: 0=f32 out, 2=bf16+relu,
//      3=qkv split: gn<2048 -> qk[m][2048] (q cols scaled 0.125*log2e),
//                   gn>=2048 -> vt[b,h,s,t] packed ushort4 scatter.
template <int EPI>
__global__ __launch_bounds__(512, 2) void gemm256(const unsigned short* __restrict__ A,
                                                  const unsigned short* __restrict__ Bt,
                                                  const float* __restrict__ bias,
                                                  void* __restrict__ Cout,
                                                  void* __restrict__ Cout2,
                                                  int N, int K, int Kstride) {
  __shared__ __align__(16) unsigned short As[4][256 * 32];  // 64 KiB ring
  __shared__ __align__(16) unsigned short Bs[4][256 * 32];  // 64 KiB ring

  int tid = threadIdx.x;
  int wv = tid >> 6, lane = tid & 63, quad = lane >> 4, l16 = lane & 15;
  int wm = wv >> 2, wn = wv & 3;  // 2x4 wave grid; wave owns 128x64 of C

  // XCD-aware bijective swizzle (gridDim.x % 8 == 0), bm-fastest
  int nwg = gridDim.x, id = blockIdx.x;
  int sid = (id & 7) * (nwg >> 3) + (id >> 3);
  int bm256 = (sid & 31) * 256, bn256 = (sid >> 5) * 256;
  int chunk = blockIdx.y;
  long kbase = (long)chunk * K;

  // staging: tile = 256 rows x 32 cols; thread covers 16B chunks tid and
  // tid+512. LDS chunk (row, slot) holds global chunk d = slot ^ ((row>>1)&3).
  int row1 = tid >> 2, row2 = row1 + 128;
  long dsl = ((tid & 3) ^ ((tid >> 3) & 3)) * 8;  // inverse-swizzled source col
  const unsigned short* Ap1 = A + (long)(bm256 + row1) * Kstride + kbase + dsl;
  const unsigned short* Ap2 = A + (long)(bm256 + row2) * Kstride + kbase + dsl;
  const unsigned short* Bp1 = Bt + (long)(bn256 + row1) * Kstride + kbase + dsl;
  const unsigned short* Bp2 = Bt + (long)(bn256 + row2) * Kstride + kbase + dsl;
  int lo1 = wv * 512, lo2 = wv * 512 + 4096;

  f32x4 acc[8][4] = {};
  // read-side swizzled 16B slot: (quad ^ ((row>>1)&3))*8, row%16 == l16
  int sl8 = (quad ^ ((l16 >> 1) & 3)) * 8;
  int arow = wm * 128 + l16;  // + i*16
  int brow = wn * 64 + l16;   // + j*16

  int NT = K >> 5;  // always >= 16 here
  // prologue stages, issue order A0 B0 A1 B1 A2 (10 loads; newest 6 may fly)
  gload_lds16(Ap1, &As[0][lo1]); gload_lds16(Ap2, &As[0][lo2]);
  gload_lds16(Bp1, &Bs[0][lo1]); gload_lds16(Bp2, &Bs[0][lo2]);
  gload_lds16(Ap1 + 32, &As[1][lo1]); gload_lds16(Ap2 + 32, &As[1][lo2]);
  gload_lds16(Bp1 + 32, &Bs[1][lo1]); gload_lds16(Bp2 + 32, &Bs[1][lo2]);
  gload_lds16(Ap1 + 64, &As[2][lo1]); gload_lds16(Ap2 + 64, &As[2][lo2]);
  asm volatile("s_waitcnt vmcnt(6)\n\ts_barrier" ::: "memory");
  __builtin_amdgcn_sched_barrier(0);

  for (int tau = 0; tau < NT; ++tau) {
    const unsigned short* Ab = &As[tau & 3][0];
    const unsigned short* Bb = &Bs[tau & 3][0];
    bf16x8 af[4], bfr[4];
    // ---- even phase: read A i0-3 + B j0-3 (8 b128); stage B(tau+2); MFMA i0-3
#pragma unroll
    for (int i = 0; i < 4; ++i)
      af[i] = *(const bf16x8*)(Ab + (arow + i * 16) * 32 + sl8);
#pragma unroll
    for (int j = 0; j < 4; ++j)
      bfr[j] = *(const bf16x8*)(Bb + (brow + j * 16) * 32 + sl8);
    if (tau + 2 < NT) {
      long ko = (long)(tau + 2) * 32;
      int s = (tau + 2) & 3;
      gload_lds16(Bp1 + ko, &Bs[s][lo1]);
      gload_lds16(Bp2 + ko, &Bs[s][lo2]);
    }
    asm volatile("s_barrier\n\ts_waitcnt lgkmcnt(0)" ::: "memory");
    __builtin_amdgcn_sched_barrier(0);
    __builtin_amdgcn_s_setprio(1);
#pragma unroll
    for (int i = 0; i < 4; ++i)
#pragma unroll
      for (int j = 0; j < 4; ++j)
        acc[i][j] = __builtin_amdgcn_mfma_f32_16x16x32_bf16(af[i], bfr[j], acc[i][j], 0, 0, 0);
    __builtin_amdgcn_s_setprio(0);
    __builtin_amdgcn_s_barrier();
    __builtin_amdgcn_sched_barrier(0);
    // ---- odd phase: read A i4-7 (4 b128); stage A(tau+3); MFMA i4-7
    bf16x8 ag[4];
#pragma unroll
    for (int i = 0; i < 4; ++i)
      ag[i] = *(const bf16x8*)(Ab + (arow + (i + 4) * 16) * 32 + sl8);
    if (tau + 3 < NT) {
      long ko = (long)(tau + 3) * 32;
      int s = (tau + 3) & 3;
      gload_lds16(Ap1 + ko, &As[s][lo1]);
      gload_lds16(Ap2 + ko, &As[s][lo2]);
    }
    asm volatile("s_barrier\n\ts_waitcnt lgkmcnt(0)" ::: "memory");
    __builtin_amdgcn_sched_barrier(0);
    __builtin_amdgcn_s_setprio(1);
#pragma unroll
    for (int i = 0; i < 4; ++i)
#pragma unroll
      for (int j = 0; j < 4; ++j)
        acc[i + 4][j] = __builtin_amdgcn_mfma_f32_16x16x32_bf16(ag[i], bfr[j], acc[i + 4][j], 0, 0, 0);
    __builtin_amdgcn_s_setprio(0);
    // ---- once-per-tile counted gate + end barrier (tail: 6 -> 4 -> 0)
    if (tau + 3 < NT) {
      asm volatile("s_waitcnt vmcnt(6)\n\ts_barrier" ::: "memory");
    } else if (tau + 2 < NT) {
      asm volatile("s_waitcnt vmcnt(4)\n\ts_barrier" ::: "memory");
    } else if (tau + 1 < NT) {
      asm volatile("s_waitcnt vmcnt(0)\n\ts_barrier" ::: "memory");
    }
    __builtin_amdgcn_sched_barrier(0);
  }

  void* Cbase = chunk ? Cout2 : Cout;
#pragma unroll
  for (int i = 0; i < 8; ++i) {
#pragma unroll
    for (int j = 0; j < 4; ++j) {
      int gn = bn256 + wn * 64 + j * 16 + l16;
      float bv = chunk ? 0.f : bias[gn];
      if (EPI == 3 && gn >= 2048) {
        int h = (gn >> 6) & 15, s = gn & 63;
        int gm0 = bm256 + wm * 128 + i * 16 + quad * 4;
        int b = gm0 >> 11, tt0 = gm0 & 2047;
        unsigned short* vt = (unsigned short*)Cout + 16777216L;
        ushort4 us;
        us.x = f2b(acc[i][j][0] + bv);
        us.y = f2b(acc[i][j][1] + bv);
        us.z = f2b(acc[i][j][2] + bv);
        us.w = f2b(acc[i][j][3] + bv);
        *(ushort4*)(vt + (((long)(b * 16 + h)) * 64 + s) * 2048 + tt0) = us;
      } else {
#pragma unroll
        for (int r = 0; r < 4; ++r) {
          int gm = bm256 + wm * 128 + i * 16 + quad * 4 + r;
          float v = acc[i][j][r] + bv;
          if (EPI == 2) v = fmaxf(v, 0.f);
          if (EPI == 0) {
            ((float*)Cbase)[(long)gm * N + gn] = v;
          } else if (EPI == 2) {
            ((unsigned short*)Cbase)[(long)gm * N + gn] = f2b(v);
          } else {  // EPI==3, q/k rows
            float sc = (gn < 1024) ? 0.18033688011112042f : 1.0f;  // 0.125*log2(e)
            ((unsigned short*)Cbase)[(long)gm * 2048 + gn] = f2b(v * sc);
          }
        }
      }
    }
  }
}

// ---------------- MFMA flash attention (reg-P, paired q-tiles, FUSED) --------
// qk[m][2048] (q cols 0..1023 pre-scaled by 0.125*log2e, k cols 1024..2047),
// vt[b,h,s,t] at elem offset 16M. 1-D grid 1024, 256 thr = 4 waves.
// id = (g&7) + 8*qa + 128*(g>>3), g = h + 16*b: the 16 pair-blocks of one
// (b,h) share an XCD. Block: q-tiles qa and qb=31-qa (64 rows each); staged
// k-tiles 0..qb serve both -> 33 works, uniform. Wave w owns q rows
// [qt*64 + w*16, +16). P fully in-register via pi-permuted K rows.
// FUSED inner loop: K-frags and V-frags are read once per (kc,aa)/(kc,sg)
// and feed BOTH q-tiles' MFMAs; two independent S^T->exp2->pack chains
// interleave for ILP.
__global__ __launch_bounds__(256) void attn_mfma(const unsigned short* __restrict__ qkv,
                                                 unsigned short* __restrict__ outp) {
  __shared__ __align__(16) unsigned short Ks[2][64 * 64];
  __shared__ __align__(16) unsigned short Vts[2][64 * 64];
  int id = blockIdx.x;
  int qa = (id >> 3) & 15, qb = 31 - qa;
  int g = (id & 7) | ((id >> 7) << 3);
  int h = g & 15, b = g >> 4;
  int t = threadIdx.x;
  int w = t >> 6, lane = t & 63, quad = lane >> 4, l16 = lane & 15;
  const unsigned short* qg = qkv + (long)(b * 2048) * 2048 + h * 64;
  const unsigned short* kg = qg + 1024;
  const unsigned short* vg = qkv + 16777216L + (((long)(b * 16 + h)) * 64) * 2048;

  // Q frags (B-operand for S^T): [ks]; row = qt*64 + w*16 + l16
  bf16x8 qfa[2], qfb[2];
#pragma unroll
  for (int ks = 0; ks < 2; ++ks) {
    qfa[ks] = *(const bf16x8*)(qg + (long)(qa * 64 + w * 16 + l16) * 2048 + ks * 32 + quad * 8);
    qfb[ks] = *(const bf16x8*)(qg + (long)(qb * 64 + w * 16 + l16) * 2048 + ks * 32 + quad * 8);
  }

  int sr = t >> 2, c4 = t & 3;
  int fsr = (sr & 3) | (((sr >> 3) & 1) << 2);          // store-side swizzle
  int ws0 = sr * 64 + (((2 * c4) ^ fsr) * 8);           // slot 2c
  int ws1 = sr * 64 + (((2 * c4 + 1) ^ fsr) * 8);       // slot 2c+1
  const unsigned short* kp = kg + (long)sr * 2048 + c4 * 16;
  const unsigned short* vp = vg + (long)sr * 2048 + c4 * 16;
  int4 kv0 = *(const int4*)kp, kv1 = *(const int4*)(kp + 8);
  int4 vv0 = *(const int4*)vp, vv1 = *(const int4*)(vp + 8);
  kp += (long)64 * 2048;
  vp += 64;

  f32x4 oa[4] = {}, ob[4] = {};
  f32x4 la = {}, lb = {};
  const short ONE = 0x3F80;
  bf16x8 ones = {ONE, ONE, ONE, ONE, ONE, ONE, ONE, ONE};

  int fs = l16 & 7;                                     // f(pi-row) for K reads
  int fv = (l16 & 3) | (((l16 >> 3) & 1) << 2);         // f(row) for V reads
  int qrow = w * 16 + l16;                              // q row within 64-tile

  int nkt = qb + 1;
  for (int kt = 0; kt < nkt; ++kt) {
    unsigned short* Kb = &Ks[kt & 1][0];
    unsigned short* Vb = &Vts[kt & 1][0];
    *(int4*)(Kb + ws0) = kv0;
    *(int4*)(Kb + ws1) = kv1;
    *(int4*)(Vb + ws0) = vv0;
    *(int4*)(Vb + ws1) = vv1;
    __syncthreads();
    if (kt + 1 < nkt) {  // prefetch next tile behind compute
      kv0 = *(const int4*)kp; kv1 = *(const int4*)(kp + 8);
      vv0 = *(const int4*)vp; vv1 = *(const int4*)(vp + 8);
      kp += (long)64 * 2048;
      vp += 64;
    }
    bool doA = (kt <= qa);
    bool diagB = (kt == qb), diagA = (kt == qa);
    // fused: K/V frags read once, both q-tiles' chains interleaved
#pragma unroll
    for (int kc = 0; kc < 2; ++kc) {
      unsigned int apwB[4], apwA[4];
#pragma unroll
      for (int aa = 0; aa < 2; ++aa) {
        int row = 8 * (l16 >> 2) + (l16 & 3) + 4 * aa + 32 * kc;  // pi(aa,kc,l16)
        const unsigned short* kr = Kb + row * 64;
        bf16x8 kf0 = *(const bf16x8*)(kr + (quad ^ fs) * 8);
        bf16x8 kf1 = *(const bf16x8*)(kr + ((quad ^ 4 ^ fs)) * 8);
        int kq = 8 * quad + 4 * aa + 32 * kc;
        f32x4 stB = {};
        stB = __builtin_amdgcn_mfma_f32_16x16x32_bf16(kf0, qfb[0], stB, 0, 0, 0);
        stB = __builtin_amdgcn_mfma_f32_16x16x32_bf16(kf1, qfb[1], stB, 0, 0, 0);
        if (diagB) {
#pragma unroll
          for (int r = 0; r < 4; ++r)
            if (kq + r > qrow) stB[r] = -1e30f;
        }
        apwB[aa * 2]     = pk2b(exp2f(stB[0]), exp2f(stB[1]));
        apwB[aa * 2 + 1] = pk2b(exp2f(stB[2]), exp2f(stB[3]));
        if (doA) {
          f32x4 stA = {};
          stA = __builtin_amdgcn_mfma_f32_16x16x32_bf16(kf0, qfa[0], stA, 0, 0, 0);
          stA = __builtin_amdgcn_mfma_f32_16x16x32_bf16(kf1, qfa[1], stA, 0, 0, 0);
          if (diagA) {
#pragma unroll
            for (int r = 0; r < 4; ++r)
              if (kq + r > qrow) stA[r] = -1e30f;
          }
          apwA[aa * 2]     = pk2b(exp2f(stA[0]), exp2f(stA[1]));
          apwA[aa * 2 + 1] = pk2b(exp2f(stA[2]), exp2f(stA[3]));
        }
      }
      union { unsigned int u[4]; bf16x8 v; } apB, apA;
#pragma unroll
      for (int u = 0; u < 4; ++u) apB.u[u] = apwB[u];
      lb = __builtin_amdgcn_mfma_f32_16x16x32_bf16(apB.v, ones, lb, 0, 0, 0);
      if (doA) {
#pragma unroll
        for (int u = 0; u < 4; ++u) apA.u[u] = apwA[u];
        la = __builtin_amdgcn_mfma_f32_16x16x32_bf16(apA.v, ones, la, 0, 0, 0);
      }
#pragma unroll
      for (int sg = 0; sg < 4; ++sg) {
        int vrow = sg * 16 + l16;
        bf16x8 vf = *(const bf16x8*)(Vb + vrow * 64 + (((4 * kc + quad) ^ fv) * 8));
        ob[sg] = __builtin_amdgcn_mfma_f32_16x16x32_bf16(apB.v, vf, ob[sg], 0, 0, 0);
        if (doA) oa[sg] = __builtin_amdgcn_mfma_f32_16x16x32_bf16(apA.v, vf, oa[sg], 0, 0, 0);
      }
    }
  }

  auto epi = [&](int qt, f32x4 (&oacc)[4], f32x4& lacc) {
#pragma unroll
    for (int r = 0; r < 4; ++r) {
      float invl = 1.f / lacc[r];
      int row = qt * 64 + w * 16 + quad * 4 + r;
      unsigned short* op = outp + ((long)(b * 2048 + row)) * 1024 + h * 64;
#pragma unroll
      for (int sg = 0; sg < 4; ++sg) op[sg * 16 + l16] = f2b(oacc[sg][r] * invl);
    }
  };
  epi(qa, oa, la);
  epi(qb, ob, lb);
}

// ---------------- residual + LayerNorm (optional 3rd addend: split-K partial) --
__global__ __launch_bounds__(256) void ln_kernel(const float* __restrict__ a,
                                                 const float* __restrict__ a2,
                                                 const float* __restrict__ res,
                                                 const float* __restrict__ gam,
                                                 const float* __restrict__ bet,
                                                 float* __restrict__ outf,
                                                 unsigned short* __restrict__ outb) {
  int row = blockIdx.x, t = threadIdx.x;
  float4 av = *(const float4*)(a + (long)row * 1024 + t * 4);
  float4 rv = *(const float4*)(res + (long)row * 1024 + t * 4);
  float v0 = av.x + rv.x, v1 = av.y + rv.y, v2 = av.z + rv.z, v3 = av.w + rv.w;
  if (a2) {
    float4 a2v = *(const float4*)(a2 + (long)row * 1024 + t * 4);
    v0 += a2v.x; v1 += a2v.y; v2 += a2v.z; v3 += a2v.w;
  }
  float s = v0 + v1 + v2 + v3;
  float ss = v0 * v0 + v1 * v1 + v2 * v2 + v3 * v3;
#pragma unroll
  for (int off = 32; off >= 1; off >>= 1) {
    s += __shfl_down(s, off);
    ss += __shfl_down(ss, off);
  }
  __shared__ float sb[4], ssb[4];
  __shared__ float mean_s, inv_s;
  int w = t >> 6, lane = t & 63;
  if (lane == 0) { sb[w] = s; ssb[w] = ss; }
  __syncthreads();
  if (t == 0) {
    float S = sb[0] + sb[1] + sb[2] + sb[3];
    float SS = ssb[0] + ssb[1] + ssb[2] + ssb[3];
    float mean = S * (1.f / 1024.f);
    float var = SS * (1.f / 1024.f) - mean * mean;
    mean_s = mean;
    inv_s = rsqrtf(var + 1e-5f);
  }
  __syncthreads();
  float mean = mean_s, inv = inv_s;
  int c = t * 4;
  float4 gv = *(const float4*)(gam + c);
  float4 bv = *(const float4*)(bet + c);
  float y0 = (v0 - mean) * inv * gv.x + bv.x;
  float y1 = (v1 - mean) * inv * gv.y + bv.y;
  float y2 = (v2 - mean) * inv * gv.z + bv.z;
  float y3 = (v3 - mean) * inv * gv.w + bv.w;
  *(float4*)(outf + (long)row * 1024 + c) = make_float4(y0, y1, y2, y3);
  if (outb) {
    *(ushort4*)(outb + (long)row * 1024 + c) = make_ushort4(f2b(y0), f2b(y1), f2b(y2), f2b(y3));
  }
}

extern "C" void kernel_launch(void* const* d_in, const int* in_sizes, int n_in,
                              void* d_out, int out_size, void* d_ws, size_t ws_size,
                              hipStream_t stream) {
  const float* x      = (const float*)d_in[0];
  const float* w_attn = (const float*)d_in[1];
  const float* b_attn = (const float*)d_in[2];
  const float* w_proj = (const float*)d_in[3];
  const float* b_proj = (const float*)d_in[4];
  const float* ln1_g  = (const float*)d_in[5];
  const float* ln1_b  = (const float*)d_in[6];
  const float* w_ff1  = (const float*)d_in[7];
  const float* b_ff1  = (const float*)d_in[8];
  const float* w_ff2  = (const float*)d_in[9];
  const float* b_ff2  = (const float*)d_in[10];
  const float* ln2_g  = (const float*)d_in[11];
  const float* ln2_b  = (const float*)d_in[12];

  const long M = 8192, E = 1024;
  char* ws = (char*)d_ws;
  unsigned short* xb   = (unsigned short*)ws; ws += M * E * 2;           // 16 MiB
  unsigned short* wTa  = (unsigned short*)ws; ws += 3072L * 1024 * 2;    // 6
  unsigned short* wTp  = (unsigned short*)ws; ws += 1024L * 1024 * 2;    // 2
  unsigned short* wTf1 = (unsigned short*)ws; ws += 4096L * 1024 * 2;    // 8
  unsigned short* wTf2 = (unsigned short*)ws; ws += 4096L * 1024 * 2;    // 8
  unsigned short* qkvb = (unsigned short*)ws; ws += M * 3072 * 2;        // 48 (qk rows 32 MiB | vt 16 MiB)
  unsigned short* attb = (unsigned short*)ws; ws += M * E * 2;           // 16
  float* a1f = (float*)ws; ws += M * E * 4;                              // 32
  float* x1f = (float*)ws; ws += M * E * 4;                              // 32
  unsigned short* x1b = (unsigned short*)ws; ws += M * E * 2;            // 16  => 184 MiB
  unsigned short* hb = qkvb;   // overlays consumed qkv+attb space
  float* f2 = a1f;
  // split-K partial buffers (reuse dead workspace, both 32 MiB fp32):
  float* prj1 = (float*)qkvb;   // qk region dead after attn; ln1 consumes before ff1
  float* ff21 = (float*)d_ws;   // xb+wTa+wTp+(part of)wTf1 dead by ff2

  cvt_bf16<<<dim3((M * E) / 4 / 256), dim3(256), 0, stream>>>(x, xb, M * E);
  transpose_bf16<<<dim3(3072 / 32, 1024 / 32), dim3(32, 8), 0, stream>>>(w_attn, wTa, 1024, 3072);
  transpose_bf16<<<dim3(1024 / 32, 1024 / 32), dim3(32, 8), 0, stream>>>(w_proj, wTp, 1024, 1024);
  transpose_bf16<<<dim3(4096 / 32, 1024 / 32), dim3(32, 8), 0, stream>>>(w_ff1, wTf1, 1024, 4096);
  transpose_bf16<<<dim3(1024 / 32, 4096 / 32), dim3(32, 8), 0, stream>>>(w_ff2, wTf2, 4096, 1024);
  // qkv projection (384 blocks), attention-layout epilogue
  gemm256<3><<<dim3(384, 1), dim3(512), 0, stream>>>(xb, wTa, b_attn, qkvb, nullptr, 3072, 1024, 1024);
  // MFMA flash attention (reg-P, paired q-tiles, fused inner loop)
  attn_mfma<<<dim3(1024), dim3(256), 0, stream>>>(qkvb, attb);
  // attn output projection: split-K=2 -> 256 blocks = 1 full round
  gemm256<0><<<dim3(128, 2), dim3(512), 0, stream>>>(attb, wTp, b_proj, a1f, prj1, 1024, 512, 1024);
  ln_kernel<<<dim3(8192), dim3(256), 0, stream>>>(a1f, prj1, x, ln1_g, ln1_b, x1f, x1b);
  // ff1 (512 blocks = 2 rounds)
  gemm256<2><<<dim3(512, 1), dim3(512), 0, stream>>>(x1b, wTf1, b_ff1, hb, nullptr, 4096, 1024, 1024);
  // ff2: split-K=2 -> 256 blocks = 1 full round, K chunks of 2048
  gemm256<0><<<dim3(128, 2), dim3(512), 0, stream>>>(hb, wTf2, b_ff2, f2, ff21, 1024, 2048, 4096);
  ln_kernel<<<dim3(8192), dim3(256), 0, stream>>>(f2, ff21, x1f, ln2_g, ln2_b, (float*)d_out, nullptr);
}

// Round 12
// 536.169 us; speedup vs baseline: 1.0471x; 1.0349x over previous
//
#include <hip/hip_runtime.h>
#include <hip/hip_bf16.h>

// GPT-2 transformer block, MI355X bf16-MFMA. Round 19:
//  - attn_mfma: EXACT R9 revert (paired q-tiles, serial two-process, 1024
//    blocks, reg-P). R10 (unpair, +occupancy) and R11 (fuse, +ILP) both
//    regressed ~8us from R9's 96us -> R9 is the local optimum; restore it.
//  - NEW prep_kernel: cvt_bf16 + 4 weight transposes merged into ONE
//    launch (13 -> 8 dispatches). Measured delta vs the pure attn revert
//    probes how much of the unaccounted ~150us is launch overhead: if
//    total drops >>8us, keep fusing; if not, the GEMMs are the remaining
//    pie and next round ports the m201 8-phase schedule faithfully.
//  - in-register P: swapped QK^T + K-row permutation pi(aa,kc,m) =
//    8*(m>>2)+(m&3)+4*aa+32*kc makes st(quad,r) hold k=8quad+(r+4aa)+32kc;
//    pk2b packs PV A-frags in-lane; P never touches LDS.
//  - Ks/Vts: LD=64, store-side XOR swizzle f(row)=(row&3)|((row>>3&1)<<2),
//    double-buffered, one barrier per k-tile. Conflict-free (0 confl).
//  - XCD grouping: id=(g&7)+8*qa+128*(g>>3) -> pair-blocks of a (b,h) on
//    one XCD (FETCH ~25MB). NO launch_bounds min-waves cap (R7/R8 lesson).
//  - gemm256 per-phase pipeline (T2+T3+T4+T5), split-K=2 + LN fusion:
//    unchanged.

typedef __attribute__((ext_vector_type(8))) short bf16x8;  // MFMA A/B frag
typedef __attribute__((ext_vector_type(4))) float f32x4;   // MFMA C/D frag

__device__ __forceinline__ unsigned short f2b(float f) {  // RNE
  unsigned int u = __float_as_uint(f);
  u += 0x7fffu + ((u >> 16) & 1u);
  return (unsigned short)(u >> 16);
}
__device__ __forceinline__ unsigned int pk2b(float a, float b) {  // packed bf16x2
  __hip_bfloat162 h = __float22bfloat162_rn(make_float2(a, b));
  return *(unsigned int*)&h;
}
__device__ __forceinline__ void gload_lds16(const unsigned short* g, unsigned short* l) {
  __builtin_amdgcn_global_load_lds((const __attribute__((address_space(1))) void*)g,
                                   (__attribute__((address_space(3))) void*)l, 16, 0, 0);
}

// ---------------- merged prep: fp32->bf16 cvt + 4 weight transposes ----------
// blocks [0,8192): cvt x (8M elems); then transpose ranges:
//   [8192,11264): w_attn 1024x3072 -> wTa;  [11264,12288): w_proj 1024^2
//   [12288,16384): w_ff1 1024x4096;         [16384,20480): w_ff2 4096x1024
__global__ __launch_bounds__(256) void prep_kernel(
    const float* __restrict__ x, unsigned short* __restrict__ xb,
    const float* __restrict__ w_attn, unsigned short* __restrict__ wTa,
    const float* __restrict__ w_proj, unsigned short* __restrict__ wTp,
    const float* __restrict__ w_ff1, unsigned short* __restrict__ wTf1,
    const float* __restrict__ w_ff2, unsigned short* __restrict__ wTf2) {
  int id = blockIdx.x;
  if (id < 8192) {  // cvt
    long i = ((long)id * 256 + threadIdx.x) * 4;
    float4 v = *(const float4*)(x + i);
    *(ushort4*)(xb + i) = make_ushort4(f2b(v.x), f2b(v.y), f2b(v.z), f2b(v.w));
    return;
  }
  id -= 8192;
  const float* in; unsigned short* out; int C, R, bx, by;
  if (id < 3072)            { in = w_attn; out = wTa;  R = 1024; C = 3072; bx = id % 96;  by = id / 96; }
  else if ((id -= 3072) < 1024) { in = w_proj; out = wTp;  R = 1024; C = 1024; bx = id % 32;  by = id / 32; }
  else if ((id -= 1024) < 4096) { in = w_ff1;  out = wTf1; R = 1024; C = 4096; bx = id % 128; by = id / 128; }
  else { id -= 4096;            in = w_ff2;  out = wTf2; R = 4096; C = 1024; bx = id % 32;  by = id / 32; }
  __shared__ float tile[32][33];
  int tx = threadIdx.x & 31, ty = threadIdx.x >> 5;
  int c0 = bx * 32, r0 = by * 32;
  for (int i = ty; i < 32; i += 8)
    tile[i][tx] = in[(long)(r0 + i) * C + c0 + tx];
  __syncthreads();
  for (int i = ty; i < 32; i += 8)
    out[(long)(c0 + i) * R + r0 + tx] = f2b(tile[tx][i]);
}

// ---------------- 256^2 per-phase-pipelined bf16 MFMA GEMM ----------------
// A [M][Kstride] bf16, Bt [N][Kstride] bf16. K = chunk length, blockIdx.y =
// K-chunk (0 -> Cout +bias, 1 -> Cout2 raw partial). M fixed 8192.
// Requires K%32==0, K>=128, N%256==0, gridDim.x%8==0.
// EPI: 0=f32 out, 2=bf16+relu,
//      3=qkv split: gn<2048 -> qk[m][2048] (q cols scaled 0.125*log2e),
//                   gn>=2048 -> vt[b,h,s,t] packed ushort4 scatter.
template <int EPI>
__global__ __launch_bounds__(512, 2) void gemm256(const unsigned short* __restrict__ A,
                                                  const unsigned short* __restrict__ Bt,
                                                  const float* __restrict__ bias,
                                                  void* __restrict__ Cout,
                                                  void* __restrict__ Cout2,
                                                  int N, int K, int Kstride) {
  __shared__ __align__(16) unsigned short As[4][256 * 32];  // 64 KiB ring
  __shared__ __align__(16) unsigned short Bs[4][256 * 32];  // 64 KiB ring

  int tid = threadIdx.x;
  int wv = tid >> 6, lane = tid & 63, quad = lane >> 4, l16 = lane & 15;
  int wm = wv >> 2, wn = wv & 3;  // 2x4 wave grid; wave owns 128x64 of C

  // XCD-aware bijective swizzle (gridDim.x % 8 == 0), bm-fastest
  int nwg = gridDim.x, id = blockIdx.x;
  int sid = (id & 7) * (nwg >> 3) + (id >> 3);
  int bm256 = (sid & 31) * 256, bn256 = (sid >> 5) * 256;
  int chunk = blockIdx.y;
  long kbase = (long)chunk * K;

  // staging: tile = 256 rows x 32 cols; thread covers 16B chunks tid and
  // tid+512. LDS chunk (row, slot) holds global chunk d = slot ^ ((row>>1)&3).
  int row1 = tid >> 2, row2 = row1 + 128;
  long dsl = ((tid & 3) ^ ((tid >> 3) & 3)) * 8;  // inverse-swizzled source col
  const unsigned short* Ap1 = A + (long)(bm256 + row1) * Kstride + kbase + dsl;
  const unsigned short* Ap2 = A + (long)(bm256 + row2) * Kstride + kbase + dsl;
  const unsigned short* Bp1 = Bt + (long)(bn256 + row1) * Kstride + kbase + dsl;
  const unsigned short* Bp2 = Bt + (long)(bn256 + row2) * Kstride + kbase + dsl;
  int lo1 = wv * 512, lo2 = wv * 512 + 4096;

  f32x4 acc[8][4] = {};
  // read-side swizzled 16B slot: (quad ^ ((row>>1)&3))*8, row%16 == l16
  int sl8 = (quad ^ ((l16 >> 1) & 3)) * 8;
  int arow = wm * 128 + l16;  // + i*16
  int brow = wn * 64 + l16;   // + j*16

  int NT = K >> 5;  // always >= 16 here
  // prologue stages, issue order A0 B0 A1 B1 A2 (10 loads; newest 6 may fly)
  gload_lds16(Ap1, &As[0][lo1]); gload_lds16(Ap2, &As[0][lo2]);
  gload_lds16(Bp1, &Bs[0][lo1]); gload_lds16(Bp2, &Bs[0][lo2]);
  gload_lds16(Ap1 + 32, &As[1][lo1]); gload_lds16(Ap2 + 32, &As[1][lo2]);
  gload_lds16(Bp1 + 32, &Bs[1][lo1]); gload_lds16(Bp2 + 32, &Bs[1][lo2]);
  gload_lds16(Ap1 + 64, &As[2][lo1]); gload_lds16(Ap2 + 64, &As[2][lo2]);
  asm volatile("s_waitcnt vmcnt(6)\n\ts_barrier" ::: "memory");
  __builtin_amdgcn_sched_barrier(0);

  for (int tau = 0; tau < NT; ++tau) {
    const unsigned short* Ab = &As[tau & 3][0];
    const unsigned short* Bb = &Bs[tau & 3][0];
    bf16x8 af[4], bfr[4];
    // ---- even phase: read A i0-3 + B j0-3 (8 b128); stage B(tau+2); MFMA i0-3
#pragma unroll
    for (int i = 0; i < 4; ++i)
      af[i] = *(const bf16x8*)(Ab + (arow + i * 16) * 32 + sl8);
#pragma unroll
    for (int j = 0; j < 4; ++j)
      bfr[j] = *(const bf16x8*)(Bb + (brow + j * 16) * 32 + sl8);
    if (tau + 2 < NT) {
      long ko = (long)(tau + 2) * 32;
      int s = (tau + 2) & 3;
      gload_lds16(Bp1 + ko, &Bs[s][lo1]);
      gload_lds16(Bp2 + ko, &Bs[s][lo2]);
    }
    asm volatile("s_barrier\n\ts_waitcnt lgkmcnt(0)" ::: "memory");
    __builtin_amdgcn_sched_barrier(0);
    __builtin_amdgcn_s_setprio(1);
#pragma unroll
    for (int i = 0; i < 4; ++i)
#pragma unroll
      for (int j = 0; j < 4; ++j)
        acc[i][j] = __builtin_amdgcn_mfma_f32_16x16x32_bf16(af[i], bfr[j], acc[i][j], 0, 0, 0);
    __builtin_amdgcn_s_setprio(0);
    __builtin_amdgcn_s_barrier();
    __builtin_amdgcn_sched_barrier(0);
    // ---- odd phase: read A i4-7 (4 b128); stage A(tau+3); MFMA i4-7
    bf16x8 ag[4];
#pragma unroll
    for (int i = 0; i < 4; ++i)
      ag[i] = *(const bf16x8*)(Ab + (arow + (i + 4) * 16) * 32 + sl8);
    if (tau + 3 < NT) {
      long ko = (long)(tau + 3) * 32;
      int s = (tau + 3) & 3;
      gload_lds16(Ap1 + ko, &As[s][lo1]);
      gload_lds16(Ap2 + ko, &As[s][lo2]);
    }
    asm volatile("s_barrier\n\ts_waitcnt lgkmcnt(0)" ::: "memory");
    __builtin_amdgcn_sched_barrier(0);
    __builtin_amdgcn_s_setprio(1);
#pragma unroll
    for (int i = 0; i < 4; ++i)
#pragma unroll
      for (int j = 0; j < 4; ++j)
        acc[i + 4][j] = __builtin_amdgcn_mfma_f32_16x16x32_bf16(ag[i], bfr[j], acc[i + 4][j], 0, 0, 0);
    __builtin_amdgcn_s_setprio(0);
    // ---- once-per-tile counted gate + end barrier (tail: 6 -> 4 -> 0)
    if (tau + 3 < NT) {
      asm volatile("s_waitcnt vmcnt(6)\n\ts_barrier" ::: "memory");
    } else if (tau + 2 < NT) {
      asm volatile("s_waitcnt vmcnt(4)\n\ts_barrier" ::: "memory");
    } else if (tau + 1 < NT) {
      asm volatile("s_waitcnt vmcnt(0)\n\ts_barrier" ::: "memory");
    }
    __builtin_amdgcn_sched_barrier(0);
  }

  void* Cbase = chunk ? Cout2 : Cout;
#pragma unroll
  for (int i = 0; i < 8; ++i) {
#pragma unroll
    for (int j = 0; j < 4; ++j) {
      int gn = bn256 + wn * 64 + j * 16 + l16;
      float bv = chunk ? 0.f : bias[gn];
      if (EPI == 3 && gn >= 2048) {
        int h = (gn >> 6) & 15, s = gn & 63;
        int gm0 = bm256 + wm * 128 + i * 16 + quad * 4;
        int b = gm0 >> 11, tt0 = gm0 & 2047;
        unsigned short* vt = (unsigned short*)Cout + 16777216L;
        ushort4 us;
        us.x = f2b(acc[i][j][0] + bv);
        us.y = f2b(acc[i][j][1] + bv);
        us.z = f2b(acc[i][j][2] + bv);
        us.w = f2b(acc[i][j][3] + bv);
        *(ushort4*)(vt + (((long)(b * 16 + h)) * 64 + s) * 2048 + tt0) = us;
      } else {
#pragma unroll
        for (int r = 0; r < 4; ++r) {
          int gm = bm256 + wm * 128 + i * 16 + quad * 4 + r;
          float v = acc[i][j][r] + bv;
          if (EPI == 2) v = fmaxf(v, 0.f);
          if (EPI == 0) {
            ((float*)Cbase)[(long)gm * N + gn] = v;
          } else if (EPI == 2) {
            ((unsigned short*)Cbase)[(long)gm * N + gn] = f2b(v);
          } else {  // EPI==3, q/k rows
            float sc = (gn < 1024) ? 0.18033688011112042f : 1.0f;  // 0.125*log2(e)
            ((unsigned short*)Cbase)[(long)gm * 2048 + gn] = f2b(v * sc);
          }
        }
      }
    }
  }
}

// ---------------- MFMA flash attention (reg-P, 64-row paired q-tiles) --------
// qk[m][2048] (q cols 0..1023 pre-scaled by 0.125*log2e, k cols 1024..2047),
// vt[b,h,s,t] at elem offset 16M. 1-D grid 1024, 256 thr = 4 waves.
// id = (g&7) + 8*qa + 128*(g>>3), g = h + 16*b: the 16 pair-blocks of one
// (b,h) share an XCD. Block: q-tiles qa and qb=31-qa (64 rows each); staged
// k-tiles 0..qb serve both -> 33 works, uniform. Wave w owns q rows
// [qt*64 + w*16, +16). P fully in-register via pi-permuted K rows.
__global__ __launch_bounds__(256) void attn_mfma(const unsigned short* __restrict__ qkv,
                                                 unsigned short* __restrict__ outp) {
  __shared__ __align__(16) unsigned short Ks[2][64 * 64];
  __shared__ __align__(16) unsigned short Vts[2][64 * 64];
  int id = blockIdx.x;
  int qa = (id >> 3) & 15, qb = 31 - qa;
  int g = (id & 7) | ((id >> 7) << 3);
  int h = g & 15, b = g >> 4;
  int t = threadIdx.x;
  int w = t >> 6, lane = t & 63, quad = lane >> 4, l16 = lane & 15;
  const unsigned short* qg = qkv + (long)(b * 2048) * 2048 + h * 64;
  const unsigned short* kg = qg + 1024;
  const unsigned short* vg = qkv + 16777216L + (((long)(b * 16 + h)) * 64) * 2048;

  // Q frags (B-operand for S^T): [ks]; row = qt*64 + w*16 + l16
  bf16x8 qfa[2], qfb[2];
#pragma unroll
  for (int ks = 0; ks < 2; ++ks) {
    qfa[ks] = *(const bf16x8*)(qg + (long)(qa * 64 + w * 16 + l16) * 2048 + ks * 32 + quad * 8);
    qfb[ks] = *(const bf16x8*)(qg + (long)(qb * 64 + w * 16 + l16) * 2048 + ks * 32 + quad * 8);
  }

  int sr = t >> 2, c4 = t & 3;
  int fsr = (sr & 3) | (((sr >> 3) & 1) << 2);          // store-side swizzle
  int ws0 = sr * 64 + (((2 * c4) ^ fsr) * 8);           // slot 2c
  int ws1 = sr * 64 + (((2 * c4 + 1) ^ fsr) * 8);       // slot 2c+1
  const unsigned short* kp = kg + (long)sr * 2048 + c4 * 16;
  const unsigned short* vp = vg + (long)sr * 2048 + c4 * 16;
  int4 kv0 = *(const int4*)kp, kv1 = *(const int4*)(kp + 8);
  int4 vv0 = *(const int4*)vp, vv1 = *(const int4*)(vp + 8);
  kp += (long)64 * 2048;
  vp += 64;

  f32x4 oa[4] = {}, ob[4] = {};
  f32x4 la = {}, lb = {};
  const short ONE = 0x3F80;
  bf16x8 ones = {ONE, ONE, ONE, ONE, ONE, ONE, ONE, ONE};

  int fs = l16 & 7;                                     // f(pi-row) for K reads
  int fv = (l16 & 3) | (((l16 >> 3) & 1) << 2);         // f(row) for V reads
  int qrow = w * 16 + l16;                              // q row within 64-tile

  // one k-tile (64 k) x 16 q rows, P fully in-register
  auto process = [&](const bf16x8 (&qf)[2], bool diag,
                     f32x4 (&oacc)[4], f32x4& lacc,
                     const unsigned short* Kb, const unsigned short* Vb) {
#pragma unroll
    for (int kc = 0; kc < 2; ++kc) {
      unsigned int apw[4];
#pragma unroll
      for (int aa = 0; aa < 2; ++aa) {
        int row = 8 * (l16 >> 2) + (l16 & 3) + 4 * aa + 32 * kc;  // pi(aa,kc,l16)
        const unsigned short* kr = Kb + row * 64;
        bf16x8 kf0 = *(const bf16x8*)(kr + (quad ^ fs) * 8);
        bf16x8 kf1 = *(const bf16x8*)(kr + ((quad ^ 4 ^ fs)) * 8);
        f32x4 st = {};
        st = __builtin_amdgcn_mfma_f32_16x16x32_bf16(kf0, qf[0], st, 0, 0, 0);
        st = __builtin_amdgcn_mfma_f32_16x16x32_bf16(kf1, qf[1], st, 0, 0, 0);
        if (diag) {
          int kq = 8 * quad + 4 * aa + 32 * kc;
#pragma unroll
          for (int r = 0; r < 4; ++r)
            if (kq + r > qrow) st[r] = -1e30f;
        }
        apw[aa * 2]     = pk2b(exp2f(st[0]), exp2f(st[1]));
        apw[aa * 2 + 1] = pk2b(exp2f(st[2]), exp2f(st[3]));
      }
      union { unsigned int u[4]; bf16x8 v; } ap;
#pragma unroll
      for (int u = 0; u < 4; ++u) ap.u[u] = apw[u];
      lacc = __builtin_amdgcn_mfma_f32_16x16x32_bf16(ap.v, ones, lacc, 0, 0, 0);
#pragma unroll
      for (int sg = 0; sg < 4; ++sg) {
        int vrow = sg * 16 + l16;
        bf16x8 vf = *(const bf16x8*)(Vb + vrow * 64 + (((4 * kc + quad) ^ fv) * 8));
        oacc[sg] = __builtin_amdgcn_mfma_f32_16x16x32_bf16(ap.v, vf, oacc[sg], 0, 0, 0);
      }
    }
  };

  int nkt = qb + 1;
  for (int kt = 0; kt < nkt; ++kt) {
    unsigned short* Kb = &Ks[kt & 1][0];
    unsigned short* Vb = &Vts[kt & 1][0];
    *(int4*)(Kb + ws0) = kv0;
    *(int4*)(Kb + ws1) = kv1;
    *(int4*)(Vb + ws0) = vv0;
    *(int4*)(Vb + ws1) = vv1;
    __syncthreads();
    if (kt + 1 < nkt) {  // prefetch next tile behind compute
      kv0 = *(const int4*)kp; kv1 = *(const int4*)(kp + 8);
      vv0 = *(const int4*)vp; vv1 = *(const int4*)(vp + 8);
      kp += (long)64 * 2048;
      vp += 64;
    }
    process(qfb, kt == qb, ob, lb, Kb, Vb);                 // heavy tile
    if (kt <= qa) process(qfa, kt == qa, oa, la, Kb, Vb);   // light tile
  }

  auto epi = [&](int qt, f32x4 (&oacc)[4], f32x4& lacc) {
#pragma unroll
    for (int r = 0; r < 4; ++r) {
      float invl = 1.f / lacc[r];
      int row = qt * 64 + w * 16 + quad * 4 + r;
      unsigned short* op = outp + ((long)(b * 2048 + row)) * 1024 + h * 64;
#pragma unroll
      for (int sg = 0; sg < 4; ++sg) op[sg * 16 + l16] = f2b(oacc[sg][r] * invl);
    }
  };
  epi(qa, oa, la);
  epi(qb, ob, lb);
}

// ---------------- residual + LayerNorm (optional 3rd addend: split-K partial) --
__global__ __launch_bounds__(256) void ln_kernel(const float* __restrict__ a,
                                                 const float* __restrict__ a2,
                                                 const float* __restrict__ res,
                                                 const float* __restrict__ gam,
                                                 const float* __restrict__ bet,
                                                 float* __restrict__ outf,
                                                 unsigned short* __restrict__ outb) {
  int row = blockIdx.x, t = threadIdx.x;
  float4 av = *(const float4*)(a + (long)row * 1024 + t * 4);
  float4 rv = *(const float4*)(res + (long)row * 1024 + t * 4);
  float v0 = av.x + rv.x, v1 = av.y + rv.y, v2 = av.z + rv.z, v3 = av.w + rv.w;
  if (a2) {
    float4 a2v = *(const float4*)(a2 + (long)row * 1024 + t * 4);
    v0 += a2v.x; v1 += a2v.y; v2 += a2v.z; v3 += a2v.w;
  }
  float s = v0 + v1 + v2 + v3;
  float ss = v0 * v0 + v1 * v1 + v2 * v2 + v3 * v3;
#pragma unroll
  for (int off = 32; off >= 1; off >>= 1) {
    s += __shfl_down(s, off);
    ss += __shfl_down(ss, off);
  }
  __shared__ float sb[4], ssb[4];
  __shared__ float mean_s, inv_s;
  int w = t >> 6, lane = t & 63;
  if (lane == 0) { sb[w] = s; ssb[w] = ss; }
  __syncthreads();
  if (t == 0) {
    float S = sb[0] + sb[1] + sb[2] + sb[3];
    float SS = ssb[0] + ssb[1] + ssb[2] + ssb[3];
    float mean = S * (1.f / 1024.f);
    float var = SS * (1.f / 1024.f) - mean * mean;
    mean_s = mean;
    inv_s = rsqrtf(var + 1e-5f);
  }
  __syncthreads();
  float mean = mean_s, inv = inv_s;
  int c = t * 4;
  float4 gv = *(const float4*)(gam + c);
  float4 bv = *(const float4*)(bet + c);
  float y0 = (v0 - mean) * inv * gv.x + bv.x;
  float y1 = (v1 - mean) * inv * gv.y + bv.y;
  float y2 = (v2 - mean) * inv * gv.z + bv.z;
  float y3 = (v3 - mean) * inv * gv.w + bv.w;
  *(float4*)(outf + (long)row * 1024 + c) = make_float4(y0, y1, y2, y3);
  if (outb) {
    *(ushort4*)(outb + (long)row * 1024 + c) = make_ushort4(f2b(y0), f2b(y1), f2b(y2), f2b(y3));
  }
}

extern "C" void kernel_launch(void* const* d_in, const int* in_sizes, int n_in,
                              void* d_out, int out_size, void* d_ws, size_t ws_size,
                              hipStream_t stream) {
  const float* x      = (const float*)d_in[0];
  const float* w_attn = (const float*)d_in[1];
  const float* b_attn = (const float*)d_in[2];
  const float* w_proj = (const float*)d_in[3];
  const float* b_proj = (const float*)d_in[4];
  const float* ln1_g  = (const float*)d_in[5];
  const float* ln1_b  = (const float*)d_in[6];
  const float* w_ff1  = (const float*)d_in[7];
  const float* b_ff1  = (const float*)d_in[8];
  const float* w_ff2  = (const float*)d_in[9];
  const float* b_ff2  = (const float*)d_in[10];
  const float* ln2_g  = (const float*)d_in[11];
  const float* ln2_b  = (const float*)d_in[12];

  const long M = 8192, E = 1024;
  char* ws = (char*)d_ws;
  unsigned short* xb   = (unsigned short*)ws; ws += M * E * 2;           // 16 MiB
  unsigned short* wTa  = (unsigned short*)ws; ws += 3072L * 1024 * 2;    // 6
  unsigned short* wTp  = (unsigned short*)ws; ws += 1024L * 1024 * 2;    // 2
  unsigned short* wTf1 = (unsigned short*)ws; ws += 4096L * 1024 * 2;    // 8
  unsigned short* wTf2 = (unsigned short*)ws; ws += 4096L * 1024 * 2;    // 8
  unsigned short* qkvb = (unsigned short*)ws; ws += M * 3072 * 2;        // 48 (qk rows 32 MiB | vt 16 MiB)
  unsigned short* attb = (unsigned short*)ws; ws += M * E * 2;           // 16
  float* a1f = (float*)ws; ws += M * E * 4;                              // 32
  float* x1f = (float*)ws; ws += M * E * 4;                              // 32
  unsigned short* x1b = (unsigned short*)ws; ws += M * E * 2;            // 16  => 184 MiB
  unsigned short* hb = qkvb;   // overlays consumed qkv+attb space
  float* f2 = a1f;
  // split-K partial buffers (reuse dead workspace, both 32 MiB fp32):
  float* prj1 = (float*)qkvb;   // qk region dead after attn; ln1 consumes before ff1
  float* ff21 = (float*)d_ws;   // xb+wTa+wTp+(part of)wTf1 dead by ff2

  // merged cvt + 4 transposes (13 -> 8 dispatches total)
  prep_kernel<<<dim3(20480), dim3(256), 0, stream>>>(x, xb, w_attn, wTa, w_proj, wTp,
                                                     w_ff1, wTf1, w_ff2, wTf2);
  // qkv projection (384 blocks), attention-layout epilogue
  gemm256<3><<<dim3(384, 1), dim3(512), 0, stream>>>(xb, wTa, b_attn, qkvb, nullptr, 3072, 1024, 1024);
  // MFMA flash attention (reg-P, paired q-tiles — R9 exact)
  attn_mfma<<<dim3(1024), dim3(256), 0, stream>>>(qkvb, attb);
  // attn output projection: split-K=2 -> 256 blocks = 1 full round
  gemm256<0><<<dim3(128, 2), dim3(512), 0, stream>>>(attb, wTp, b_proj, a1f, prj1, 1024, 512, 1024);
  ln_kernel<<<dim3(8192), dim3(256), 0, stream>>>(a1f, prj1, x, ln1_g, ln1_b, x1f, x1b);
  // ff1 (512 blocks = 2 rounds)
  gemm256<2><<<dim3(512, 1), dim3(512), 0, stream>>>(x1b, wTf1, b_ff1, hb, nullptr, 4096, 1024, 1024);
  // ff2: split-K=2 -> 256 blocks = 1 full round, K chunks of 2048
  gemm256<0><<<dim3(128, 2), dim3(512), 0, stream>>>(hb, wTf2, b_ff2, f2, ff21, 1024, 2048, 4096);
  ln_kernel<<<dim3(8192), dim3(256), 0, stream>>>(f2, ff21, x1f, ln2_g, ln2_b, (float*)d_out, nullptr);
}

// Round 13
// 533.127 us; speedup vs baseline: 1.0531x; 1.0057x over previous
//
#include <hip/hip_runtime.h>
#include <hip/hip_bf16.h>

// GPT-2 transformer block, MI355X bf16-MFMA. Round 20:
//  - gemm256: REMOVED all sched_barrier(0) fences from the K-loop (added in
//    R10 as defensive fencing). m141 measured sched_barrier(0) order-pinning
//    at 874->510 TF on the m97 kernel — it defeats hipcc's own fine-grained
//    scheduling, and the m201 template (1563 TF) uses none. Correctness
//    holds without them: ds_read/global_load_lds are compiler-visible
//    memory ops ordered by the asm "memory" clobbers; MFMA operands are
//    compiler-tracked ds_read results (hipcc auto-inserts lgkmcnt before
//    use — rule-18's hazard is only for inline-asm ds_reads).
//    Everything else in gemm256 byte-identical to R12 (clean A/B).
//  - attn_mfma: R9-exact (paired q-tiles, reg-P, 96us measured). Unchanged.
//  - prep_kernel (merged cvt + 4 transposes), split-K=2 + LN fusion:
//    unchanged from R12 (536us session best).

typedef __attribute__((ext_vector_type(8))) short bf16x8;  // MFMA A/B frag
typedef __attribute__((ext_vector_type(4))) float f32x4;   // MFMA C/D frag

__device__ __forceinline__ unsigned short f2b(float f) {  // RNE
  unsigned int u = __float_as_uint(f);
  u += 0x7fffu + ((u >> 16) & 1u);
  return (unsigned short)(u >> 16);
}
__device__ __forceinline__ unsigned int pk2b(float a, float b) {  // packed bf16x2
  __hip_bfloat162 h = __float22bfloat162_rn(make_float2(a, b));
  return *(unsigned int*)&h;
}
__device__ __forceinline__ void gload_lds16(const unsigned short* g, unsigned short* l) {
  __builtin_amdgcn_global_load_lds((const __attribute__((address_space(1))) void*)g,
                                   (__attribute__((address_space(3))) void*)l, 16, 0, 0);
}

// ---------------- merged prep: fp32->bf16 cvt + 4 weight transposes ----------
__global__ __launch_bounds__(256) void prep_kernel(
    const float* __restrict__ x, unsigned short* __restrict__ xb,
    const float* __restrict__ w_attn, unsigned short* __restrict__ wTa,
    const float* __restrict__ w_proj, unsigned short* __restrict__ wTp,
    const float* __restrict__ w_ff1, unsigned short* __restrict__ wTf1,
    const float* __restrict__ w_ff2, unsigned short* __restrict__ wTf2) {
  int id = blockIdx.x;
  if (id < 8192) {  // cvt
    long i = ((long)id * 256 + threadIdx.x) * 4;
    float4 v = *(const float4*)(x + i);
    *(ushort4*)(xb + i) = make_ushort4(f2b(v.x), f2b(v.y), f2b(v.z), f2b(v.w));
    return;
  }
  id -= 8192;
  const float* in; unsigned short* out; int C, R, bx, by;
  if (id < 3072)            { in = w_attn; out = wTa;  R = 1024; C = 3072; bx = id % 96;  by = id / 96; }
  else if ((id -= 3072) < 1024) { in = w_proj; out = wTp;  R = 1024; C = 1024; bx = id % 32;  by = id / 32; }
  else if ((id -= 1024) < 4096) { in = w_ff1;  out = wTf1; R = 1024; C = 4096; bx = id % 128; by = id / 128; }
  else { id -= 4096;            in = w_ff2;  out = wTf2; R = 4096; C = 1024; bx = id % 32;  by = id / 32; }
  __shared__ float tile[32][33];
  int tx = threadIdx.x & 31, ty = threadIdx.x >> 5;
  int c0 = bx * 32, r0 = by * 32;
  for (int i = ty; i < 32; i += 8)
    tile[i][tx] = in[(long)(r0 + i) * C + c0 + tx];
  __syncthreads();
  for (int i = ty; i < 32; i += 8)
    out[(long)(c0 + i) * R + r0 + tx] = f2b(tile[tx][i]);
}

// ---------------- 256^2 per-phase-pipelined bf16 MFMA GEMM ----------------
// A [M][Kstride] bf16, Bt [N][Kstride] bf16. K = chunk length, blockIdx.y =
// K-chunk (0 -> Cout +bias, 1 -> Cout2 raw partial). M fixed 8192.
// Requires K%32==0, K>=128, N%256==0, gridDim.x%8==0.
// EPI: 0=f32 out, 2=bf16+relu,
//      3=qkv split: gn<2048 -> qk[m][2048] (q cols scaled 0.125*log2e),
//                   gn>=2048 -> vt[b,h,s,t] packed ushort4 scatter.
template <int EPI>
__global__ __launch_bounds__(512, 2) void gemm256(const unsigned short* __restrict__ A,
                                                  const unsigned short* __restrict__ Bt,
                                                  const float* __restrict__ bias,
                                                  void* __restrict__ Cout,
                                                  void* __restrict__ Cout2,
                                                  int N, int K, int Kstride) {
  __shared__ __align__(16) unsigned short As[4][256 * 32];  // 64 KiB ring
  __shared__ __align__(16) unsigned short Bs[4][256 * 32];  // 64 KiB ring

  int tid = threadIdx.x;
  int wv = tid >> 6, lane = tid & 63, quad = lane >> 4, l16 = lane & 15;
  int wm = wv >> 2, wn = wv & 3;  // 2x4 wave grid; wave owns 128x64 of C

  // XCD-aware bijective swizzle (gridDim.x % 8 == 0), bm-fastest
  int nwg = gridDim.x, id = blockIdx.x;
  int sid = (id & 7) * (nwg >> 3) + (id >> 3);
  int bm256 = (sid & 31) * 256, bn256 = (sid >> 5) * 256;
  int chunk = blockIdx.y;
  long kbase = (long)chunk * K;

  // staging: tile = 256 rows x 32 cols; thread covers 16B chunks tid and
  // tid+512. LDS chunk (row, slot) holds global chunk d = slot ^ ((row>>1)&3).
  int row1 = tid >> 2, row2 = row1 + 128;
  long dsl = ((tid & 3) ^ ((tid >> 3) & 3)) * 8;  // inverse-swizzled source col
  const unsigned short* Ap1 = A + (long)(bm256 + row1) * Kstride + kbase + dsl;
  const unsigned short* Ap2 = A + (long)(bm256 + row2) * Kstride + kbase + dsl;
  const unsigned short* Bp1 = Bt + (long)(bn256 + row1) * Kstride + kbase + dsl;
  const unsigned short* Bp2 = Bt + (long)(bn256 + row2) * Kstride + kbase + dsl;
  int lo1 = wv * 512, lo2 = wv * 512 + 4096;

  f32x4 acc[8][4] = {};
  // read-side swizzled 16B slot: (quad ^ ((row>>1)&3))*8, row%16 == l16
  int sl8 = (quad ^ ((l16 >> 1) & 3)) * 8;
  int arow = wm * 128 + l16;  // + i*16
  int brow = wn * 64 + l16;   // + j*16

  int NT = K >> 5;  // always >= 16 here
  // prologue stages, issue order A0 B0 A1 B1 A2 (10 loads; newest 6 may fly)
  gload_lds16(Ap1, &As[0][lo1]); gload_lds16(Ap2, &As[0][lo2]);
  gload_lds16(Bp1, &Bs[0][lo1]); gload_lds16(Bp2, &Bs[0][lo2]);
  gload_lds16(Ap1 + 32, &As[1][lo1]); gload_lds16(Ap2 + 32, &As[1][lo2]);
  gload_lds16(Bp1 + 32, &Bs[1][lo1]); gload_lds16(Bp2 + 32, &Bs[1][lo2]);
  gload_lds16(Ap1 + 64, &As[2][lo1]); gload_lds16(Ap2 + 64, &As[2][lo2]);
  asm volatile("s_waitcnt vmcnt(6)\n\ts_barrier" ::: "memory");

  for (int tau = 0; tau < NT; ++tau) {
    const unsigned short* Ab = &As[tau & 3][0];
    const unsigned short* Bb = &Bs[tau & 3][0];
    bf16x8 af[4], bfr[4];
    // ---- even phase: read A i0-3 + B j0-3 (8 b128); stage B(tau+2); MFMA i0-3
#pragma unroll
    for (int i = 0; i < 4; ++i)
      af[i] = *(const bf16x8*)(Ab + (arow + i * 16) * 32 + sl8);
#pragma unroll
    for (int j = 0; j < 4; ++j)
      bfr[j] = *(const bf16x8*)(Bb + (brow + j * 16) * 32 + sl8);
    if (tau + 2 < NT) {
      long ko = (long)(tau + 2) * 32;
      int s = (tau + 2) & 3;
      gload_lds16(Bp1 + ko, &Bs[s][lo1]);
      gload_lds16(Bp2 + ko, &Bs[s][lo2]);
    }
    asm volatile("s_barrier\n\ts_waitcnt lgkmcnt(0)" ::: "memory");
    __builtin_amdgcn_s_setprio(1);
#pragma unroll
    for (int i = 0; i < 4; ++i)
#pragma unroll
      for (int j = 0; j < 4; ++j)
        acc[i][j] = __builtin_amdgcn_mfma_f32_16x16x32_bf16(af[i], bfr[j], acc[i][j], 0, 0, 0);
    __builtin_amdgcn_s_setprio(0);
    __builtin_amdgcn_s_barrier();
    // ---- odd phase: read A i4-7 (4 b128); stage A(tau+3); MFMA i4-7
    bf16x8 ag[4];
#pragma unroll
    for (int i = 0; i < 4; ++i)
      ag[i] = *(const bf16x8*)(Ab + (arow + (i + 4) * 16) * 32 + sl8);
    if (tau + 3 < NT) {
      long ko = (long)(tau + 3) * 32;
      int s = (tau + 3) & 3;
      gload_lds16(Ap1 + ko, &As[s][lo1]);
      gload_lds16(Ap2 + ko, &As[s][lo2]);
    }
    asm volatile("s_barrier\n\ts_waitcnt lgkmcnt(0)" ::: "memory");
    __builtin_amdgcn_s_setprio(1);
#pragma unroll
    for (int i = 0; i < 4; ++i)
#pragma unroll
      for (int j = 0; j < 4; ++j)
        acc[i + 4][j] = __builtin_amdgcn_mfma_f32_16x16x32_bf16(ag[i], bfr[j], acc[i + 4][j], 0, 0, 0);
    __builtin_amdgcn_s_setprio(0);
    // ---- once-per-tile counted gate + end barrier (tail: 6 -> 4 -> 0)
    if (tau + 3 < NT) {
      asm volatile("s_waitcnt vmcnt(6)\n\ts_barrier" ::: "memory");
    } else if (tau + 2 < NT) {
      asm volatile("s_waitcnt vmcnt(4)\n\ts_barrier" ::: "memory");
    } else if (tau + 1 < NT) {
      asm volatile("s_waitcnt vmcnt(0)\n\ts_barrier" ::: "memory");
    }
  }

  void* Cbase = chunk ? Cout2 : Cout;
#pragma unroll
  for (int i = 0; i < 8; ++i) {
#pragma unroll
    for (int j = 0; j < 4; ++j) {
      int gn = bn256 + wn * 64 + j * 16 + l16;
      float bv = chunk ? 0.f : bias[gn];
      if (EPI == 3 && gn >= 2048) {
        int h = (gn >> 6) & 15, s = gn & 63;
        int gm0 = bm256 + wm * 128 + i * 16 + quad * 4;
        int b = gm0 >> 11, tt0 = gm0 & 2047;
        unsigned short* vt = (unsigned short*)Cout + 16777216L;
        ushort4 us;
        us.x = f2b(acc[i][j][0] + bv);
        us.y = f2b(acc[i][j][1] + bv);
        us.z = f2b(acc[i][j][2] + bv);
        us.w = f2b(acc[i][j][3] + bv);
        *(ushort4*)(vt + (((long)(b * 16 + h)) * 64 + s) * 2048 + tt0) = us;
      } else {
#pragma unroll
        for (int r = 0; r < 4; ++r) {
          int gm = bm256 + wm * 128 + i * 16 + quad * 4 + r;
          float v = acc[i][j][r] + bv;
          if (EPI == 2) v = fmaxf(v, 0.f);
          if (EPI == 0) {
            ((float*)Cbase)[(long)gm * N + gn] = v;
          } else if (EPI == 2) {
            ((unsigned short*)Cbase)[(long)gm * N + gn] = f2b(v);
          } else {  // EPI==3, q/k rows
            float sc = (gn < 1024) ? 0.18033688011112042f : 1.0f;  // 0.125*log2(e)
            ((unsigned short*)Cbase)[(long)gm * 2048 + gn] = f2b(v * sc);
          }
        }
      }
    }
  }
}

// ---------------- MFMA flash attention (reg-P, 64-row paired q-tiles) --------
// qk[m][2048] (q cols 0..1023 pre-scaled by 0.125*log2e, k cols 1024..2047),
// vt[b,h,s,t] at elem offset 16M. 1-D grid 1024, 256 thr = 4 waves.
// id = (g&7) + 8*qa + 128*(g>>3), g = h + 16*b: the 16 pair-blocks of one
// (b,h) share an XCD. Block: q-tiles qa and qb=31-qa (64 rows each); staged
// k-tiles 0..qb serve both -> 33 works, uniform. Wave w owns q rows
// [qt*64 + w*16, +16). P fully in-register via pi-permuted K rows.
__global__ __launch_bounds__(256) void attn_mfma(const unsigned short* __restrict__ qkv,
                                                 unsigned short* __restrict__ outp) {
  __shared__ __align__(16) unsigned short Ks[2][64 * 64];
  __shared__ __align__(16) unsigned short Vts[2][64 * 64];
  int id = blockIdx.x;
  int qa = (id >> 3) & 15, qb = 31 - qa;
  int g = (id & 7) | ((id >> 7) << 3);
  int h = g & 15, b = g >> 4;
  int t = threadIdx.x;
  int w = t >> 6, lane = t & 63, quad = lane >> 4, l16 = lane & 15;
  const unsigned short* qg = qkv + (long)(b * 2048) * 2048 + h * 64;
  const unsigned short* kg = qg + 1024;
  const unsigned short* vg = qkv + 16777216L + (((long)(b * 16 + h)) * 64) * 2048;

  // Q frags (B-operand for S^T): [ks]; row = qt*64 + w*16 + l16
  bf16x8 qfa[2], qfb[2];
#pragma unroll
  for (int ks = 0; ks < 2; ++ks) {
    qfa[ks] = *(const bf16x8*)(qg + (long)(qa * 64 + w * 16 + l16) * 2048 + ks * 32 + quad * 8);
    qfb[ks] = *(const bf16x8*)(qg + (long)(qb * 64 + w * 16 + l16) * 2048 + ks * 32 + quad * 8);
  }

  int sr = t >> 2, c4 = t & 3;
  int fsr = (sr & 3) | (((sr >> 3) & 1) << 2);          // store-side swizzle
  int ws0 = sr * 64 + (((2 * c4) ^ fsr) * 8);           // slot 2c
  int ws1 = sr * 64 + (((2 * c4 + 1) ^ fsr) * 8);       // slot 2c+1
  const unsigned short* kp = kg + (long)sr * 2048 + c4 * 16;
  const unsigned short* vp = vg + (long)sr * 2048 + c4 * 16;
  int4 kv0 = *(const int4*)kp, kv1 = *(const int4*)(kp + 8);
  int4 vv0 = *(const int4*)vp, vv1 = *(const int4*)(vp + 8);
  kp += (long)64 * 2048;
  vp += 64;

  f32x4 oa[4] = {}, ob[4] = {};
  f32x4 la = {}, lb = {};
  const short ONE = 0x3F80;
  bf16x8 ones = {ONE, ONE, ONE, ONE, ONE, ONE, ONE, ONE};

  int fs = l16 & 7;                                     // f(pi-row) for K reads
  int fv = (l16 & 3) | (((l16 >> 3) & 1) << 2);         // f(row) for V reads
  int qrow = w * 16 + l16;                              // q row within 64-tile

  // one k-tile (64 k) x 16 q rows, P fully in-register
  auto process = [&](const bf16x8 (&qf)[2], bool diag,
                     f32x4 (&oacc)[4], f32x4& lacc,
                     const unsigned short* Kb, const unsigned short* Vb) {
#pragma unroll
    for (int kc = 0; kc < 2; ++kc) {
      unsigned int apw[4];
#pragma unroll
      for (int aa = 0; aa < 2; ++aa) {
        int row = 8 * (l16 >> 2) + (l16 & 3) + 4 * aa + 32 * kc;  // pi(aa,kc,l16)
        const unsigned short* kr = Kb + row * 64;
        bf16x8 kf0 = *(const bf16x8*)(kr + (quad ^ fs) * 8);
        bf16x8 kf1 = *(const bf16x8*)(kr + ((quad ^ 4 ^ fs)) * 8);
        f32x4 st = {};
        st = __builtin_amdgcn_mfma_f32_16x16x32_bf16(kf0, qf[0], st, 0, 0, 0);
        st = __builtin_amdgcn_mfma_f32_16x16x32_bf16(kf1, qf[1], st, 0, 0, 0);
        if (diag) {
          int kq = 8 * quad + 4 * aa + 32 * kc;
#pragma unroll
          for (int r = 0; r < 4; ++r)
            if (kq + r > qrow) st[r] = -1e30f;
        }
        apw[aa * 2]     = pk2b(exp2f(st[0]), exp2f(st[1]));
        apw[aa * 2 + 1] = pk2b(exp2f(st[2]), exp2f(st[3]));
      }
      union { unsigned int u[4]; bf16x8 v; } ap;
#pragma unroll
      for (int u = 0; u < 4; ++u) ap.u[u] = apw[u];
      lacc = __builtin_amdgcn_mfma_f32_16x16x32_bf16(ap.v, ones, lacc, 0, 0, 0);
#pragma unroll
      for (int sg = 0; sg < 4; ++sg) {
        int vrow = sg * 16 + l16;
        bf16x8 vf = *(const bf16x8*)(Vb + vrow * 64 + (((4 * kc + quad) ^ fv) * 8));
        oacc[sg] = __builtin_amdgcn_mfma_f32_16x16x32_bf16(ap.v, vf, oacc[sg], 0, 0, 0);
      }
    }
  };

  int nkt = qb + 1;
  for (int kt = 0; kt < nkt; ++kt) {
    unsigned short* Kb = &Ks[kt & 1][0];
    unsigned short* Vb = &Vts[kt & 1][0];
    *(int4*)(Kb + ws0) = kv0;
    *(int4*)(Kb + ws1) = kv1;
    *(int4*)(Vb + ws0) = vv0;
    *(int4*)(Vb + ws1) = vv1;
    __syncthreads();
    if (kt + 1 < nkt) {  // prefetch next tile behind compute
      kv0 = *(const int4*)kp; kv1 = *(const int4*)(kp + 8);
      vv0 = *(const int4*)vp; vv1 = *(const int4*)(vp + 8);
      kp += (long)64 * 2048;
      vp += 64;
    }
    process(qfb, kt == qb, ob, lb, Kb, Vb);                 // heavy tile
    if (kt <= qa) process(qfa, kt == qa, oa, la, Kb, Vb);   // light tile
  }

  auto epi = [&](int qt, f32x4 (&oacc)[4], f32x4& lacc) {
#pragma unroll
    for (int r = 0; r < 4; ++r) {
      float invl = 1.f / lacc[r];
      int row = qt * 64 + w * 16 + quad * 4 + r;
      unsigned short* op = outp + ((long)(b * 2048 + row)) * 1024 + h * 64;
#pragma unroll
      for (int sg = 0; sg < 4; ++sg) op[sg * 16 + l16] = f2b(oacc[sg][r] * invl);
    }
  };
  epi(qa, oa, la);
  epi(qb, ob, lb);
}

// ---------------- residual + LayerNorm (optional 3rd addend: split-K partial) --
__global__ __launch_bounds__(256) void ln_kernel(const float* __restrict__ a,
                                                 const float* __restrict__ a2,
                                                 const float* __restrict__ res,
                                                 const float* __restrict__ gam,
                                                 const float* __restrict__ bet,
                                                 float* __restrict__ outf,
                                                 unsigned short* __restrict__ outb) {
  int row = blockIdx.x, t = threadIdx.x;
  float4 av = *(const float4*)(a + (long)row * 1024 + t * 4);
  float4 rv = *(const float4*)(res + (long)row * 1024 + t * 4);
  float v0 = av.x + rv.x, v1 = av.y + rv.y, v2 = av.z + rv.z, v3 = av.w + rv.w;
  if (a2) {
    float4 a2v = *(const float4*)(a2 + (long)row * 1024 + t * 4);
    v0 += a2v.x; v1 += a2v.y; v2 += a2v.z; v3 += a2v.w;
  }
  float s = v0 + v1 + v2 + v3;
  float ss = v0 * v0 + v1 * v1 + v2 * v2 + v3 * v3;
#pragma unroll
  for (int off = 32; off >= 1; off >>= 1) {
    s += __shfl_down(s, off);
    ss += __shfl_down(ss, off);
  }
  __shared__ float sb[4], ssb[4];
  __shared__ float mean_s, inv_s;
  int w = t >> 6, lane = t & 63;
  if (lane == 0) { sb[w] = s; ssb[w] = ss; }
  __syncthreads();
  if (t == 0) {
    float S = sb[0] + sb[1] + sb[2] + sb[3];
    float SS = ssb[0] + ssb[1] + ssb[2] + ssb[3];
    float mean = S * (1.f / 1024.f);
    float var = SS * (1.f / 1024.f) - mean * mean;
    mean_s = mean;
    inv_s = rsqrtf(var + 1e-5f);
  }
  __syncthreads();
  float mean = mean_s, inv = inv_s;
  int c = t * 4;
  float4 gv = *(const float4*)(gam + c);
  float4 bv = *(const float4*)(bet + c);
  float y0 = (v0 - mean) * inv * gv.x + bv.x;
  float y1 = (v1 - mean) * inv * gv.y + bv.y;
  float y2 = (v2 - mean) * inv * gv.z + bv.z;
  float y3 = (v3 - mean) * inv * gv.w + bv.w;
  *(float4*)(outf + (long)row * 1024 + c) = make_float4(y0, y1, y2, y3);
  if (outb) {
    *(ushort4*)(outb + (long)row * 1024 + c) = make_ushort4(f2b(y0), f2b(y1), f2b(y2), f2b(y3));
  }
}

extern "C" void kernel_launch(void* const* d_in, const int* in_sizes, int n_in,
                              void* d_out, int out_size, void* d_ws, size_t ws_size,
                              hipStream_t stream) {
  const float* x      = (const float*)d_in[0];
  const float* w_attn = (const float*)d_in[1];
  const float* b_attn = (const float*)d_in[2];
  const float* w_proj = (const float*)d_in[3];
  const float* b_proj = (const float*)d_in[4];
  const float* ln1_g  = (const float*)d_in[5];
  const float* ln1_b  = (const float*)d_in[6];
  const float* w_ff1  = (const float*)d_in[7];
  const float* b_ff1  = (const float*)d_in[8];
  const float* w_ff2  = (const float*)d_in[9];
  const float* b_ff2  = (const float*)d_in[10];
  const float* ln2_g  = (const float*)d_in[11];
  const float* ln2_b  = (const float*)d_in[12];

  const long M = 8192, E = 1024;
  char* ws = (char*)d_ws;
  unsigned short* xb   = (unsigned short*)ws; ws += M * E * 2;           // 16 MiB
  unsigned short* wTa  = (unsigned short*)ws; ws += 3072L * 1024 * 2;    // 6
  unsigned short* wTp  = (unsigned short*)ws; ws += 1024L * 1024 * 2;    // 2
  unsigned short* wTf1 = (unsigned short*)ws; ws += 4096L * 1024 * 2;    // 8
  unsigned short* wTf2 = (unsigned short*)ws; ws += 4096L * 1024 * 2;    // 8
  unsigned short* qkvb = (unsigned short*)ws; ws += M * 3072 * 2;        // 48 (qk rows 32 MiB | vt 16 MiB)
  unsigned short* attb = (unsigned short*)ws; ws += M * E * 2;           // 16
  float* a1f = (float*)ws; ws += M * E * 4;                              // 32
  float* x1f = (float*)ws; ws += M * E * 4;                              // 32
  unsigned short* x1b = (unsigned short*)ws; ws += M * E * 2;            // 16  => 184 MiB
  unsigned short* hb = qkvb;   // overlays consumed qkv+attb space
  float* f2 = a1f;
  // split-K partial buffers (reuse dead workspace, both 32 MiB fp32):
  float* prj1 = (float*)qkvb;   // qk region dead after attn; ln1 consumes before ff1
  float* ff21 = (float*)d_ws;   // xb+wTa+wTp+(part of)wTf1 dead by ff2

  // merged cvt + 4 transposes
  prep_kernel<<<dim3(20480), dim3(256), 0, stream>>>(x, xb, w_attn, wTa, w_proj, wTp,
                                                     w_ff1, wTf1, w_ff2, wTf2);
  // qkv projection (384 blocks), attention-layout epilogue
  gemm256<3><<<dim3(384, 1), dim3(512), 0, stream>>>(xb, wTa, b_attn, qkvb, nullptr, 3072, 1024, 1024);
  // MFMA flash attention (reg-P, paired q-tiles — R9 exact)
  attn_mfma<<<dim3(1024), dim3(256), 0, stream>>>(qkvb, attb);
  // attn output projection: split-K=2 -> 256 blocks = 1 full round
  gemm256<0><<<dim3(128, 2), dim3(512), 0, stream>>>(attb, wTp, b_proj, a1f, prj1, 1024, 512, 1024);
  ln_kernel<<<dim3(8192), dim3(256), 0, stream>>>(a1f, prj1, x, ln1_g, ln1_b, x1f, x1b);
  // ff1 (512 blocks = 2 rounds)
  gemm256<2><<<dim3(512, 1), dim3(512), 0, stream>>>(x1b, wTf1, b_ff1, hb, nullptr, 4096, 1024, 1024);
  // ff2: split-K=2 -> 256 blocks = 1 full round, K chunks of 2048
  gemm256<0><<<dim3(128, 2), dim3(512), 0, stream>>>(hb, wTf2, b_ff2, f2, ff21, 1024, 2048, 4096);
  ln_kernel<<<dim3(8192), dim3(256), 0, stream>>>(f2, ff21, x1f, ln2_g, ln2_b, (float*)d_out, nullptr);
}

// Round 14
// 518.044 us; speedup vs baseline: 1.0837x; 1.0291x over previous
//
#include <hip/hip_runtime.h>
#include <hip/hip_bf16.h>

// GPT-2 transformer block, MI355X bf16-MFMA. Round 21:
//  - gemm256 (two targeted fixes on the R13 kernel; phase structure intact):
//    (a) 2-D XCD clustering: bm=(xcd*4+(r&3)), bn=r>>2 (was bm-fastest).
//        R13 counters: qkv FETCH 101 MiB vs 22 ideal — each XCD's cluster
//        spanned ALL 32 bm tiles, so every XCD re-read the whole A matrix
//        from HBM (8x replication, 26% stage L2-miss at ~900cy lengthening
//        every vmcnt gate). Now each XCD reads 4 A-panels + its B columns.
//        Valid for all grids (nwg%32==0: 384/512/128).
//    (b) symmetric depth-3 prefetch: stage BOTH A(t+3) and B(t+3) (B was
//        depth-2, the shallowest gate cover). Gate vmcnt(8) steady, 4 -> 0
//        tail. Ledger: 4 live buffers distinct mod 4 (read t&3; in-flight
//        (t+1)&3,(t+2)&3; write (t+3)&3=(t-1)&3, last read before the
//        gate(t-1) barrier). Prologue stages tiles 0,1,2 fully (12 loads),
//        waits vmcnt(8).
//  - attn_mfma: R9-exact (paired q-tiles, reg-P, 96us). Unchanged.
//  - prep_kernel, split-K=2 + LN fusion: unchanged (533us base).

typedef __attribute__((ext_vector_type(8))) short bf16x8;  // MFMA A/B frag
typedef __attribute__((ext_vector_type(4))) float f32x4;   // MFMA C/D frag

__device__ __forceinline__ unsigned short f2b(float f) {  // RNE
  unsigned int u = __float_as_uint(f);
  u += 0x7fffu + ((u >> 16) & 1u);
  return (unsigned short)(u >> 16);
}
__device__ __forceinline__ unsigned int pk2b(float a, float b) {  // packed bf16x2
  __hip_bfloat162 h = __float22bfloat162_rn(make_float2(a, b));
  return *(unsigned int*)&h;
}
__device__ __forceinline__ void gload_lds16(const unsigned short* g, unsigned short* l) {
  __builtin_amdgcn_global_load_lds((const __attribute__((address_space(1))) void*)g,
                                   (__attribute__((address_space(3))) void*)l, 16, 0, 0);
}

// ---------------- merged prep: fp32->bf16 cvt + 4 weight transposes ----------
__global__ __launch_bounds__(256) void prep_kernel(
    const float* __restrict__ x, unsigned short* __restrict__ xb,
    const float* __restrict__ w_attn, unsigned short* __restrict__ wTa,
    const float* __restrict__ w_proj, unsigned short* __restrict__ wTp,
    const float* __restrict__ w_ff1, unsigned short* __restrict__ wTf1,
    const float* __restrict__ w_ff2, unsigned short* __restrict__ wTf2) {
  int id = blockIdx.x;
  if (id < 8192) {  // cvt
    long i = ((long)id * 256 + threadIdx.x) * 4;
    float4 v = *(const float4*)(x + i);
    *(ushort4*)(xb + i) = make_ushort4(f2b(v.x), f2b(v.y), f2b(v.z), f2b(v.w));
    return;
  }
  id -= 8192;
  const float* in; unsigned short* out; int C, R, bx, by;
  if (id < 3072)            { in = w_attn; out = wTa;  R = 1024; C = 3072; bx = id % 96;  by = id / 96; }
  else if ((id -= 3072) < 1024) { in = w_proj; out = wTp;  R = 1024; C = 1024; bx = id % 32;  by = id / 32; }
  else if ((id -= 1024) < 4096) { in = w_ff1;  out = wTf1; R = 1024; C = 4096; bx = id % 128; by = id / 128; }
  else { id -= 4096;            in = w_ff2;  out = wTf2; R = 4096; C = 1024; bx = id % 32;  by = id / 32; }
  __shared__ float tile[32][33];
  int tx = threadIdx.x & 31, ty = threadIdx.x >> 5;
  int c0 = bx * 32, r0 = by * 32;
  for (int i = ty; i < 32; i += 8)
    tile[i][tx] = in[(long)(r0 + i) * C + c0 + tx];
  __syncthreads();
  for (int i = ty; i < 32; i += 8)
    out[(long)(c0 + i) * R + r0 + tx] = f2b(tile[tx][i]);
}

// ---------------- 256^2 per-phase-pipelined bf16 MFMA GEMM ----------------
// A [M][Kstride] bf16, Bt [N][Kstride] bf16. K = chunk length, blockIdx.y =
// K-chunk (0 -> Cout +bias, 1 -> Cout2 raw partial). M fixed 8192.
// Requires K%32==0, K>=128, N%256==0, gridDim.x%32==0 (2-D XCD clusters).
// EPI: 0=f32 out, 2=bf16+relu,
//      3=qkv split: gn<2048 -> qk[m][2048] (q cols scaled 0.125*log2e),
//                   gn>=2048 -> vt[b,h,s,t] packed ushort4 scatter.
template <int EPI>
__global__ __launch_bounds__(512, 2) void gemm256(const unsigned short* __restrict__ A,
                                                  const unsigned short* __restrict__ Bt,
                                                  const float* __restrict__ bias,
                                                  void* __restrict__ Cout,
                                                  void* __restrict__ Cout2,
                                                  int N, int K, int Kstride) {
  __shared__ __align__(16) unsigned short As[4][256 * 32];  // 64 KiB ring
  __shared__ __align__(16) unsigned short Bs[4][256 * 32];  // 64 KiB ring

  int tid = threadIdx.x;
  int wv = tid >> 6, lane = tid & 63, quad = lane >> 4, l16 = lane & 15;
  int wm = wv >> 2, wn = wv & 3;  // 2x4 wave grid; wave owns 128x64 of C

  // 2-D XCD clustering: XCD x owns bm-tiles [4x,4x+4) x all bn (A read once
  // per 4-bm stripe per XCD instead of whole-A per XCD). nwg%32==0 required.
  int id = blockIdx.x;
  int xcd = id & 7, r = id >> 3;
  int bm256 = (xcd * 4 + (r & 3)) * 256;
  int bn256 = (r >> 2) * 256;
  int chunk = blockIdx.y;
  long kbase = (long)chunk * K;

  // staging: tile = 256 rows x 32 cols; thread covers 16B chunks tid and
  // tid+512. LDS chunk (row, slot) holds global chunk d = slot ^ ((row>>1)&3).
  int row1 = tid >> 2, row2 = row1 + 128;
  long dsl = ((tid & 3) ^ ((tid >> 3) & 3)) * 8;  // inverse-swizzled source col
  const unsigned short* Ap1 = A + (long)(bm256 + row1) * Kstride + kbase + dsl;
  const unsigned short* Ap2 = A + (long)(bm256 + row2) * Kstride + kbase + dsl;
  const unsigned short* Bp1 = Bt + (long)(bn256 + row1) * Kstride + kbase + dsl;
  const unsigned short* Bp2 = Bt + (long)(bn256 + row2) * Kstride + kbase + dsl;
  int lo1 = wv * 512, lo2 = wv * 512 + 4096;

  f32x4 acc[8][4] = {};
  // read-side swizzled 16B slot: (quad ^ ((row>>1)&3))*8, row%16 == l16
  int sl8 = (quad ^ ((l16 >> 1) & 3)) * 8;
  int arow = wm * 128 + l16;  // + i*16
  int brow = wn * 64 + l16;   // + j*16

  int NT = K >> 5;  // always >= 16 here
  // prologue: stage tiles 0,1,2 fully (12 loads); wait tile 0 (8 may fly)
  gload_lds16(Ap1, &As[0][lo1]); gload_lds16(Ap2, &As[0][lo2]);
  gload_lds16(Bp1, &Bs[0][lo1]); gload_lds16(Bp2, &Bs[0][lo2]);
  gload_lds16(Ap1 + 32, &As[1][lo1]); gload_lds16(Ap2 + 32, &As[1][lo2]);
  gload_lds16(Bp1 + 32, &Bs[1][lo1]); gload_lds16(Bp2 + 32, &Bs[1][lo2]);
  gload_lds16(Ap1 + 64, &As[2][lo1]); gload_lds16(Ap2 + 64, &As[2][lo2]);
  gload_lds16(Bp1 + 64, &Bs[2][lo1]); gload_lds16(Bp2 + 64, &Bs[2][lo2]);
  asm volatile("s_waitcnt vmcnt(8)\n\ts_barrier" ::: "memory");

  for (int tau = 0; tau < NT; ++tau) {
    const unsigned short* Ab = &As[tau & 3][0];
    const unsigned short* Bb = &Bs[tau & 3][0];
    bf16x8 af[4], bfr[4];
    // ---- even phase: read A i0-3 + B j0-3 (8 b128); stage B(tau+3); MFMA i0-3
#pragma unroll
    for (int i = 0; i < 4; ++i)
      af[i] = *(const bf16x8*)(Ab + (arow + i * 16) * 32 + sl8);
#pragma unroll
    for (int j = 0; j < 4; ++j)
      bfr[j] = *(const bf16x8*)(Bb + (brow + j * 16) * 32 + sl8);
    if (tau + 3 < NT) {
      long ko = (long)(tau + 3) * 32;
      int s = (tau + 3) & 3;
      gload_lds16(Bp1 + ko, &Bs[s][lo1]);
      gload_lds16(Bp2 + ko, &Bs[s][lo2]);
    }
    asm volatile("s_barrier\n\ts_waitcnt lgkmcnt(0)" ::: "memory");
    __builtin_amdgcn_s_setprio(1);
#pragma unroll
    for (int i = 0; i < 4; ++i)
#pragma unroll
      for (int j = 0; j < 4; ++j)
        acc[i][j] = __builtin_amdgcn_mfma_f32_16x16x32_bf16(af[i], bfr[j], acc[i][j], 0, 0, 0);
    __builtin_amdgcn_s_setprio(0);
    __builtin_amdgcn_s_barrier();
    // ---- odd phase: read A i4-7 (4 b128); stage A(tau+3); MFMA i4-7
    bf16x8 ag[4];
#pragma unroll
    for (int i = 0; i < 4; ++i)
      ag[i] = *(const bf16x8*)(Ab + (arow + (i + 4) * 16) * 32 + sl8);
    if (tau + 3 < NT) {
      long ko = (long)(tau + 3) * 32;
      int s = (tau + 3) & 3;
      gload_lds16(Ap1 + ko, &As[s][lo1]);
      gload_lds16(Ap2 + ko, &As[s][lo2]);
    }
    asm volatile("s_barrier\n\ts_waitcnt lgkmcnt(0)" ::: "memory");
    __builtin_amdgcn_s_setprio(1);
#pragma unroll
    for (int i = 0; i < 4; ++i)
#pragma unroll
      for (int j = 0; j < 4; ++j)
        acc[i + 4][j] = __builtin_amdgcn_mfma_f32_16x16x32_bf16(ag[i], bfr[j], acc[i + 4][j], 0, 0, 0);
    __builtin_amdgcn_s_setprio(0);
    // ---- once-per-tile counted gate + end barrier (tail: 8 -> 4 -> 0)
    if (tau + 3 < NT) {
      asm volatile("s_waitcnt vmcnt(8)\n\ts_barrier" ::: "memory");
    } else if (tau + 2 < NT) {
      asm volatile("s_waitcnt vmcnt(4)\n\ts_barrier" ::: "memory");
    } else if (tau + 1 < NT) {
      asm volatile("s_waitcnt vmcnt(0)\n\ts_barrier" ::: "memory");
    }
  }

  void* Cbase = chunk ? Cout2 : Cout;
#pragma unroll
  for (int i = 0; i < 8; ++i) {
#pragma unroll
    for (int j = 0; j < 4; ++j) {
      int gn = bn256 + wn * 64 + j * 16 + l16;
      float bv = chunk ? 0.f : bias[gn];
      if (EPI == 3 && gn >= 2048) {
        int h = (gn >> 6) & 15, s = gn & 63;
        int gm0 = bm256 + wm * 128 + i * 16 + quad * 4;
        int b = gm0 >> 11, tt0 = gm0 & 2047;
        unsigned short* vt = (unsigned short*)Cout + 16777216L;
        ushort4 us;
        us.x = f2b(acc[i][j][0] + bv);
        us.y = f2b(acc[i][j][1] + bv);
        us.z = f2b(acc[i][j][2] + bv);
        us.w = f2b(acc[i][j][3] + bv);
        *(ushort4*)(vt + (((long)(b * 16 + h)) * 64 + s) * 2048 + tt0) = us;
      } else {
#pragma unroll
        for (int r2 = 0; r2 < 4; ++r2) {
          int gm = bm256 + wm * 128 + i * 16 + quad * 4 + r2;
          float v = acc[i][j][r2] + bv;
          if (EPI == 2) v = fmaxf(v, 0.f);
          if (EPI == 0) {
            ((float*)Cbase)[(long)gm * N + gn] = v;
          } else if (EPI == 2) {
            ((unsigned short*)Cbase)[(long)gm * N + gn] = f2b(v);
          } else {  // EPI==3, q/k rows
            float sc = (gn < 1024) ? 0.18033688011112042f : 1.0f;  // 0.125*log2(e)
            ((unsigned short*)Cbase)[(long)gm * 2048 + gn] = f2b(v * sc);
          }
        }
      }
    }
  }
}

// ---------------- MFMA flash attention (reg-P, 64-row paired q-tiles) --------
// qk[m][2048] (q cols 0..1023 pre-scaled by 0.125*log2e, k cols 1024..2047),
// vt[b,h,s,t] at elem offset 16M. 1-D grid 1024, 256 thr = 4 waves.
// id = (g&7) + 8*qa + 128*(g>>3), g = h + 16*b: the 16 pair-blocks of one
// (b,h) share an XCD. Block: q-tiles qa and qb=31-qa (64 rows each); staged
// k-tiles 0..qb serve both -> 33 works, uniform. Wave w owns q rows
// [qt*64 + w*16, +16). P fully in-register via pi-permuted K rows.
__global__ __launch_bounds__(256) void attn_mfma(const unsigned short* __restrict__ qkv,
                                                 unsigned short* __restrict__ outp) {
  __shared__ __align__(16) unsigned short Ks[2][64 * 64];
  __shared__ __align__(16) unsigned short Vts[2][64 * 64];
  int id = blockIdx.x;
  int qa = (id >> 3) & 15, qb = 31 - qa;
  int g = (id & 7) | ((id >> 7) << 3);
  int h = g & 15, b = g >> 4;
  int t = threadIdx.x;
  int w = t >> 6, lane = t & 63, quad = lane >> 4, l16 = lane & 15;
  const unsigned short* qg = qkv + (long)(b * 2048) * 2048 + h * 64;
  const unsigned short* kg = qg + 1024;
  const unsigned short* vg = qkv + 16777216L + (((long)(b * 16 + h)) * 64) * 2048;

  // Q frags (B-operand for S^T): [ks]; row = qt*64 + w*16 + l16
  bf16x8 qfa[2], qfb[2];
#pragma unroll
  for (int ks = 0; ks < 2; ++ks) {
    qfa[ks] = *(const bf16x8*)(qg + (long)(qa * 64 + w * 16 + l16) * 2048 + ks * 32 + quad * 8);
    qfb[ks] = *(const bf16x8*)(qg + (long)(qb * 64 + w * 16 + l16) * 2048 + ks * 32 + quad * 8);
  }

  int sr = t >> 2, c4 = t & 3;
  int fsr = (sr & 3) | (((sr >> 3) & 1) << 2);          // store-side swizzle
  int ws0 = sr * 64 + (((2 * c4) ^ fsr) * 8);           // slot 2c
  int ws1 = sr * 64 + (((2 * c4 + 1) ^ fsr) * 8);       // slot 2c+1
  const unsigned short* kp = kg + (long)sr * 2048 + c4 * 16;
  const unsigned short* vp = vg + (long)sr * 2048 + c4 * 16;
  int4 kv0 = *(const int4*)kp, kv1 = *(const int4*)(kp + 8);
  int4 vv0 = *(const int4*)vp, vv1 = *(const int4*)(vp + 8);
  kp += (long)64 * 2048;
  vp += 64;

  f32x4 oa[4] = {}, ob[4] = {};
  f32x4 la = {}, lb = {};
  const short ONE = 0x3F80;
  bf16x8 ones = {ONE, ONE, ONE, ONE, ONE, ONE, ONE, ONE};

  int fs = l16 & 7;                                     // f(pi-row) for K reads
  int fv = (l16 & 3) | (((l16 >> 3) & 1) << 2);         // f(row) for V reads
  int qrow = w * 16 + l16;                              // q row within 64-tile

  // one k-tile (64 k) x 16 q rows, P fully in-register
  auto process = [&](const bf16x8 (&qf)[2], bool diag,
                     f32x4 (&oacc)[4], f32x4& lacc,
                     const unsigned short* Kb, const unsigned short* Vb) {
#pragma unroll
    for (int kc = 0; kc < 2; ++kc) {
      unsigned int apw[4];
#pragma unroll
      for (int aa = 0; aa < 2; ++aa) {
        int row = 8 * (l16 >> 2) + (l16 & 3) + 4 * aa + 32 * kc;  // pi(aa,kc,l16)
        const unsigned short* kr = Kb + row * 64;
        bf16x8 kf0 = *(const bf16x8*)(kr + (quad ^ fs) * 8);
        bf16x8 kf1 = *(const bf16x8*)(kr + ((quad ^ 4 ^ fs)) * 8);
        f32x4 st = {};
        st = __builtin_amdgcn_mfma_f32_16x16x32_bf16(kf0, qf[0], st, 0, 0, 0);
        st = __builtin_amdgcn_mfma_f32_16x16x32_bf16(kf1, qf[1], st, 0, 0, 0);
        if (diag) {
          int kq = 8 * quad + 4 * aa + 32 * kc;
#pragma unroll
          for (int r = 0; r < 4; ++r)
            if (kq + r > qrow) st[r] = -1e30f;
        }
        apw[aa * 2]     = pk2b(exp2f(st[0]), exp2f(st[1]));
        apw[aa * 2 + 1] = pk2b(exp2f(st[2]), exp2f(st[3]));
      }
      union { unsigned int u[4]; bf16x8 v; } ap;
#pragma unroll
      for (int u = 0; u < 4; ++u) ap.u[u] = apw[u];
      lacc = __builtin_amdgcn_mfma_f32_16x16x32_bf16(ap.v, ones, lacc, 0, 0, 0);
#pragma unroll
      for (int sg = 0; sg < 4; ++sg) {
        int vrow = sg * 16 + l16;
        bf16x8 vf = *(const bf16x8*)(Vb + vrow * 64 + (((4 * kc + quad) ^ fv) * 8));
        oacc[sg] = __builtin_amdgcn_mfma_f32_16x16x32_bf16(ap.v, vf, oacc[sg], 0, 0, 0);
      }
    }
  };

  int nkt = qb + 1;
  for (int kt = 0; kt < nkt; ++kt) {
    unsigned short* Kb = &Ks[kt & 1][0];
    unsigned short* Vb = &Vts[kt & 1][0];
    *(int4*)(Kb + ws0) = kv0;
    *(int4*)(Kb + ws1) = kv1;
    *(int4*)(Vb + ws0) = vv0;
    *(int4*)(Vb + ws1) = vv1;
    __syncthreads();
    if (kt + 1 < nkt) {  // prefetch next tile behind compute
      kv0 = *(const int4*)kp; kv1 = *(const int4*)(kp + 8);
      vv0 = *(const int4*)vp; vv1 = *(const int4*)(vp + 8);
      kp += (long)64 * 2048;
      vp += 64;
    }
    process(qfb, kt == qb, ob, lb, Kb, Vb);                 // heavy tile
    if (kt <= qa) process(qfa, kt == qa, oa, la, Kb, Vb);   // light tile
  }

  auto epi = [&](int qt, f32x4 (&oacc)[4], f32x4& lacc) {
#pragma unroll
    for (int r = 0; r < 4; ++r) {
      float invl = 1.f / lacc[r];
      int row = qt * 64 + w * 16 + quad * 4 + r;
      unsigned short* op = outp + ((long)(b * 2048 + row)) * 1024 + h * 64;
#pragma unroll
      for (int sg = 0; sg < 4; ++sg) op[sg * 16 + l16] = f2b(oacc[sg][r] * invl);
    }
  };
  epi(qa, oa, la);
  epi(qb, ob, lb);
}

// ---------------- residual + LayerNorm (optional 3rd addend: split-K partial) --
__global__ __launch_bounds__(256) void ln_kernel(const float* __restrict__ a,
                                                 const float* __restrict__ a2,
                                                 const float* __restrict__ res,
                                                 const float* __restrict__ gam,
                                                 const float* __restrict__ bet,
                                                 float* __restrict__ outf,
                                                 unsigned short* __restrict__ outb) {
  int row = blockIdx.x, t = threadIdx.x;
  float4 av = *(const float4*)(a + (long)row * 1024 + t * 4);
  float4 rv = *(const float4*)(res + (long)row * 1024 + t * 4);
  float v0 = av.x + rv.x, v1 = av.y + rv.y, v2 = av.z + rv.z, v3 = av.w + rv.w;
  if (a2) {
    float4 a2v = *(const float4*)(a2 + (long)row * 1024 + t * 4);
    v0 += a2v.x; v1 += a2v.y; v2 += a2v.z; v3 += a2v.w;
  }
  float s = v0 + v1 + v2 + v3;
  float ss = v0 * v0 + v1 * v1 + v2 * v2 + v3 * v3;
#pragma unroll
  for (int off = 32; off >= 1; off >>= 1) {
    s += __shfl_down(s, off);
    ss += __shfl_down(ss, off);
  }
  __shared__ float sb[4], ssb[4];
  __shared__ float mean_s, inv_s;
  int w = t >> 6, lane = t & 63;
  if (lane == 0) { sb[w] = s; ssb[w] = ss; }
  __syncthreads();
  if (t == 0) {
    float S = sb[0] + sb[1] + sb[2] + sb[3];
    float SS = ssb[0] + ssb[1] + ssb[2] + ssb[3];
    float mean = S * (1.f / 1024.f);
    float var = SS * (1.f / 1024.f) - mean * mean;
    mean_s = mean;
    inv_s = rsqrtf(var + 1e-5f);
  }
  __syncthreads();
  float mean = mean_s, inv = inv_s;
  int c = t * 4;
  float4 gv = *(const float4*)(gam + c);
  float4 bv = *(const float4*)(bet + c);
  float y0 = (v0 - mean) * inv * gv.x + bv.x;
  float y1 = (v1 - mean) * inv * gv.y + bv.y;
  float y2 = (v2 - mean) * inv * gv.z + bv.z;
  float y3 = (v3 - mean) * inv * gv.w + bv.w;
  *(float4*)(outf + (long)row * 1024 + c) = make_float4(y0, y1, y2, y3);
  if (outb) {
    *(ushort4*)(outb + (long)row * 1024 + c) = make_ushort4(f2b(y0), f2b(y1), f2b(y2), f2b(y3));
  }
}

extern "C" void kernel_launch(void* const* d_in, const int* in_sizes, int n_in,
                              void* d_out, int out_size, void* d_ws, size_t ws_size,
                              hipStream_t stream) {
  const float* x      = (const float*)d_in[0];
  const float* w_attn = (const float*)d_in[1];
  const float* b_attn = (const float*)d_in[2];
  const float* w_proj = (const float*)d_in[3];
  const float* b_proj = (const float*)d_in[4];
  const float* ln1_g  = (const float*)d_in[5];
  const float* ln1_b  = (const float*)d_in[6];
  const float* w_ff1  = (const float*)d_in[7];
  const float* b_ff1  = (const float*)d_in[8];
  const float* w_ff2  = (const float*)d_in[9];
  const float* b_ff2  = (const float*)d_in[10];
  const float* ln2_g  = (const float*)d_in[11];
  const float* ln2_b  = (const float*)d_in[12];

  const long M = 8192, E = 1024;
  char* ws = (char*)d_ws;
  unsigned short* xb   = (unsigned short*)ws; ws += M * E * 2;           // 16 MiB
  unsigned short* wTa  = (unsigned short*)ws; ws += 3072L * 1024 * 2;    // 6
  unsigned short* wTp  = (unsigned short*)ws; ws += 1024L * 1024 * 2;    // 2
  unsigned short* wTf1 = (unsigned short*)ws; ws += 4096L * 1024 * 2;    // 8
  unsigned short* wTf2 = (unsigned short*)ws; ws += 4096L * 1024 * 2;    // 8
  unsigned short* qkvb = (unsigned short*)ws; ws += M * 3072 * 2;        // 48 (qk rows 32 MiB | vt 16 MiB)
  unsigned short* attb = (unsigned short*)ws; ws += M * E * 2;           // 16
  float* a1f = (float*)ws; ws += M * E * 4;                              // 32
  float* x1f = (float*)ws; ws += M * E * 4;                              // 32
  unsigned short* x1b = (unsigned short*)ws; ws += M * E * 2;            // 16  => 184 MiB
  unsigned short* hb = qkvb;   // overlays consumed qkv+attb space
  float* f2 = a1f;
  // split-K partial buffers (reuse dead workspace, both 32 MiB fp32):
  float* prj1 = (float*)qkvb;   // qk region dead after attn; ln1 consumes before ff1
  float* ff21 = (float*)d_ws;   // xb+wTa+wTp+(part of)wTf1 dead by ff2

  // merged cvt + 4 transposes
  prep_kernel<<<dim3(20480), dim3(256), 0, stream>>>(x, xb, w_attn, wTa, w_proj, wTp,
                                                     w_ff1, wTf1, w_ff2, wTf2);
  // qkv projection (384 blocks), attention-layout epilogue
  gemm256<3><<<dim3(384, 1), dim3(512), 0, stream>>>(xb, wTa, b_attn, qkvb, nullptr, 3072, 1024, 1024);
  // MFMA flash attention (reg-P, paired q-tiles — R9 exact)
  attn_mfma<<<dim3(1024), dim3(256), 0, stream>>>(qkvb, attb);
  // attn output projection: split-K=2 -> 256 blocks = 1 full round
  gemm256<0><<<dim3(128, 2), dim3(512), 0, stream>>>(attb, wTp, b_proj, a1f, prj1, 1024, 512, 1024);
  ln_kernel<<<dim3(8192), dim3(256), 0, stream>>>(a1f, prj1, x, ln1_g, ln1_b, x1f, x1b);
  // ff1 (512 blocks = 2 rounds)
  gemm256<2><<<dim3(512, 1), dim3(512), 0, stream>>>(x1b, wTf1, b_ff1, hb, nullptr, 4096, 1024, 1024);
  // ff2: split-K=2 -> 256 blocks = 1 full round, K chunks of 2048
  gemm256<0><<<dim3(128, 2), dim3(512), 0, stream>>>(hb, wTf2, b_ff2, f2, ff21, 1024, 2048, 4096);
  ln_kernel<<<dim3(8192), dim3(256), 0, stream>>>(f2, ff21, x1f, ln2_g, ln2_b, (float*)d_out, nullptr);
}